// Round 1
// baseline (646.989 us; speedup 1.0000x reference)
//
#include <hip/hip_runtime.h>
#include <math.h>

#define N_NODES 100000
#define N_EDGES 3200000
#define N_GRAPHS 64
#define IN_DIM 128
#define HID 64
#define BN_EPS 1e-5f

#define PSHIFT 9
#define PBS 512
#define NPB ((N_NODES + PBS - 1) / PBS)  // 196
#define PART_BLOCKS 256
#define CHUNK_E (N_EDGES / PART_BLOCKS)  // 12500 (multiple of 4)

#define QBOUND 25000
#define NB_AGG ((N_NODES + 63) / 64)  // 1563: 16 groups/block x 4 nodes/group

typedef unsigned short ushort_t;
typedef __attribute__((ext_vector_type(8))) short bf16x8;
typedef __attribute__((ext_vector_type(4))) float f32x4;

__device__ __forceinline__ float bflo(unsigned u) { return __uint_as_float(u << 16); }
__device__ __forceinline__ float bfhi(unsigned u) { return __uint_as_float(u & 0xFFFF0000u); }
__device__ __forceinline__ float bfu(ushort_t u) { return __uint_as_float((unsigned)u << 16); }
__device__ __forceinline__ unsigned f2bf(float f) {  // RNE
  unsigned u = __float_as_uint(f);
  return (u + 0x7FFFu + ((u >> 16) & 1u)) >> 16;
}

// ---------------- CSR build: two-level bucket sort, int4-vectorized ----------------

__global__ __launch_bounds__(256) void ghist_k(const int* __restrict__ ei,
                                               int* __restrict__ gh) {
  __shared__ int h[NPB];
  for (int i = threadIdx.x; i < NPB; i += 256) h[i] = 0;
  __syncthreads();
  const int4* d4 = (const int4*)(ei + N_EDGES);
  int n4 = N_EDGES / 4;
  int stride = gridDim.x * 256;
  for (int i = blockIdx.x * 256 + threadIdx.x; i < n4; i += stride) {
    int4 d = d4[i];
    atomicAdd(&h[d.x >> PSHIFT], 1);
    atomicAdd(&h[d.y >> PSHIFT], 1);
    atomicAdd(&h[d.z >> PSHIFT], 1);
    atomicAdd(&h[d.w >> PSHIFT], 1);
  }
  __syncthreads();
  for (int i = threadIdx.x; i < NPB; i += 256) {
    int v = h[i];
    if (v) atomicAdd(&gh[i], v);
  }
}

__global__ __launch_bounds__(256) void gscan_k(const int* __restrict__ gh,
                                               int* __restrict__ boff,
                                               int* __restrict__ gcur) {
  __shared__ int sa[256], sb[256];
  int t = threadIdx.x;
  int v = (t < NPB) ? gh[t] : 0;
  sa[t] = v;
  __syncthreads();
  int* src = sa; int* dst = sb;
  for (int o = 1; o < 256; o <<= 1) {
    dst[t] = src[t] + ((t >= o) ? src[t - o] : 0);
    __syncthreads();
    int* tmp = src; src = dst; dst = tmp;
  }
  if (t < NPB) {
    int excl = src[t] - v;
    boff[t] = excl;
    gcur[t] = excl;
    if (t == NPB - 1) boff[NPB] = src[t];
  }
}

__global__ __launch_bounds__(512) void part_k(const int* __restrict__ ei,
                                              int* __restrict__ gcur,
                                              unsigned* __restrict__ tmp) {
  __shared__ int lh[NPB];
  __shared__ int lcur[NPB];
  int t = threadIdx.x;
  for (int i = t; i < NPB; i += 512) lh[i] = 0;
  __syncthreads();
  int q0 = blockIdx.x * (CHUNK_E / 4);
  int q1 = q0 + CHUNK_E / 4;
  const int4* d4 = (const int4*)(ei + N_EDGES);
  const int4* s4 = (const int4*)ei;
  for (int i = q0 + t; i < q1; i += 512) {
    int4 d = d4[i];
    atomicAdd(&lh[d.x >> PSHIFT], 1);
    atomicAdd(&lh[d.y >> PSHIFT], 1);
    atomicAdd(&lh[d.z >> PSHIFT], 1);
    atomicAdd(&lh[d.w >> PSHIFT], 1);
  }
  __syncthreads();
  for (int i = t; i < NPB; i += 512) {
    int v = lh[i];
    lcur[i] = v ? atomicAdd(&gcur[i], v) : 0;
  }
  __syncthreads();
  for (int i = q0 + t; i < q1; i += 512) {
    int4 d = d4[i];
    int4 s = s4[i];
    int b0 = d.x >> PSHIFT, b1 = d.y >> PSHIFT, b2 = d.z >> PSHIFT, b3 = d.w >> PSHIFT;
    int p0 = atomicAdd(&lcur[b0], 1);
    int p1 = atomicAdd(&lcur[b1], 1);
    int p2 = atomicAdd(&lcur[b2], 1);
    int p3 = atomicAdd(&lcur[b3], 1);
    tmp[p0] = ((unsigned)(d.x & (PBS - 1)) << 17) | (unsigned)s.x;
    tmp[p1] = ((unsigned)(d.y & (PBS - 1)) << 17) | (unsigned)s.y;
    tmp[p2] = ((unsigned)(d.z & (PBS - 1)) << 17) | (unsigned)s.z;
    tmp[p3] = ((unsigned)(d.w & (PBS - 1)) << 17) | (unsigned)s.w;
  }
}

// fused per-bucket: histogram per (node, src-quartile) -> rp4/dinv -> place
// rp4[4n+k] = start of node n's src-quartile-k segment (quartile-sorted CSR)
__global__ __launch_bounds__(512) void bwork_k(
    const unsigned* __restrict__ tmp, const int* __restrict__ boff,
    int* __restrict__ rp4, float* __restrict__ dinv, int* __restrict__ csr) {
  int b = blockIdx.x;
  int base = boff[b], end = boff[b + 1];
  int t = threadIdx.x;
  __shared__ int cnt[PBS * 4];
  __shared__ int cur[PBS * 4];
  __shared__ int sa[PBS], sb[PBS];
  for (int i = t; i < PBS * 4; i += 512) cnt[i] = 0;
  __syncthreads();
  int a0 = (base + 3) & ~3;
  int a1 = end & ~3;
  if (a1 < a0) { a0 = end; a1 = end; }
  const uint4* t4 = (const uint4*)tmp;
#define HIST1(U) { unsigned u_ = (U); int nl_ = u_ >> 17; int s_ = u_ & 0x1FFFF; \
    int qq_ = (s_ >= QBOUND) + (s_ >= 2*QBOUND) + (s_ >= 3*QBOUND); \
    atomicAdd(&cnt[nl_ * 4 + qq_], 1); }
  if (base + t < a0) HIST1(tmp[base + t]);
  for (int i = a0 / 4 + t; i < a1 / 4; i += 512) {
    uint4 u = t4[i];
    HIST1(u.x) HIST1(u.y) HIST1(u.z) HIST1(u.w)
  }
  if (a1 + t < end) HIST1(tmp[a1 + t]);
#undef HIST1
  __syncthreads();
  int c0 = cnt[t * 4], c1 = cnt[t * 4 + 1], c2 = cnt[t * 4 + 2], c3 = cnt[t * 4 + 3];
  int tsum = c0 + c1 + c2 + c3;
  sa[t] = tsum;
  __syncthreads();
  int* src_ = sa; int* dst_ = sb;
  for (int o = 1; o < PBS; o <<= 1) {
    dst_[t] = src_[t] + ((t >= o) ? src_[t - o] : 0);
    __syncthreads();
    int* z = src_; src_ = dst_; dst_ = z;
  }
  int nb = src_[t] - tsum;
  int o0 = nb, o1 = nb + c0, o2 = nb + c0 + c1, o3 = nb + c0 + c1 + c2;
  cur[t * 4] = o0; cur[t * 4 + 1] = o1; cur[t * 4 + 2] = o2; cur[t * 4 + 3] = o3;
  int n = b * PBS + t;
  if (n < N_NODES) {
    rp4[4 * n] = base + o0;
    rp4[4 * n + 1] = base + o1;
    rp4[4 * n + 2] = base + o2;
    rp4[4 * n + 3] = base + o3;
    dinv[n] = rsqrtf((float)(tsum + 1));  // +1 self loop
    if (n == N_NODES - 1) rp4[4 * N_NODES] = base + nb + tsum;
  }
  __syncthreads();
#define PLACE1(U) { unsigned u_ = (U); int nl_ = u_ >> 17; int s_ = u_ & 0x1FFFF; \
    int qq_ = (s_ >= QBOUND) + (s_ >= 2*QBOUND) + (s_ >= 3*QBOUND); \
    int p_ = atomicAdd(&cur[nl_ * 4 + qq_], 1); \
    csr[base + p_] = s_ << 7; }
  if (base + t < a0) PLACE1(tmp[base + t]);
  for (int i = a0 / 4 + t; i < a1 / 4; i += 512) {
    uint4 u = t4[i];
    PLACE1(u.x) PLACE1(u.y) PLACE1(u.z) PLACE1(u.w)
  }
  if (a1 + t < end) PLACE1(tmp[a1 + t]);
#undef PLACE1
}

// ---------------- MFMA GEMM: hs[n][c] = dinv[n] * (BN(X)[n] @ W)[c] -> bf16 ----------------

template <int K, bool XBF16, bool APPLY, bool RELU>
__global__ __launch_bounds__(256) void gemm_k(
    const void* __restrict__ Xv, const float* __restrict__ W,
    const float* __restrict__ sums, const float* __restrict__ gamma,
    const float* __restrict__ beta, const float* __restrict__ dinv,
    ushort_t* __restrict__ out, int nrows) {
  __shared__ ushort_t wt[64 * K];   // wt[n][k] bf16
  __shared__ float scs[128], shs[128];
  __shared__ float redo[64 * 65];   // D repack, padded
  const int tid = threadIdx.x;
  const int wv = tid >> 6;
  const int lane = tid & 63;
  const int lm = lane & 15;
  const int lq = lane >> 4;

  for (int idx = tid; idx < K * 64; idx += 256) {
    int k = idx >> 6, c = idx & 63;      // W[k][c]
    wt[c * K + k] = (ushort_t)f2bf(W[idx]);
  }
  if (APPLY) {
    for (int k = tid; k < K; k += 256) {
      float m = sums[k] / (float)N_NODES;
      float v = sums[64 + k] / (float)N_NODES - m * m;
      float s = gamma[k] * rsqrtf(v + BN_EPS);
      scs[k] = s;
      shs[k] = beta[k] - m * s;
    }
  }
  __syncthreads();

  const int rowbase = blockIdx.x * 64;
  const int grow = rowbase + wv * 16 + lm;
  const bool valid = grow < nrows;
  f32x4 acc0 = {0.f, 0.f, 0.f, 0.f};
  f32x4 acc1 = acc0, acc2 = acc0, acc3 = acc0;

#pragma unroll
  for (int k0 = 0; k0 < K; k0 += 32) {
    int kbase = k0 + lq * 8;
    bf16x8 a = {0, 0, 0, 0, 0, 0, 0, 0};
    if (valid) {
      if (XBF16) {
        uint4 u = *(const uint4*)((const char*)Xv + ((size_t)grow * 64 + kbase) * 2);
        if (APPLY) {
          float4 sc0 = *(const float4*)&scs[kbase];
          float4 sc1 = *(const float4*)&scs[kbase + 4];
          float4 sh0 = *(const float4*)&shs[kbase];
          float4 sh1 = *(const float4*)&shs[kbase + 4];
          float f0 = bflo(u.x) * sc0.x + sh0.x, f1 = bfhi(u.x) * sc0.y + sh0.y;
          float f2 = bflo(u.y) * sc0.z + sh0.z, f3 = bfhi(u.y) * sc0.w + sh0.w;
          float f4 = bflo(u.z) * sc1.x + sh1.x, f5 = bfhi(u.z) * sc1.y + sh1.y;
          float f6 = bflo(u.w) * sc1.z + sh1.z, f7 = bfhi(u.w) * sc1.w + sh1.w;
          if (RELU) {
            f0 = fmaxf(f0, 0.f); f1 = fmaxf(f1, 0.f);
            f2 = fmaxf(f2, 0.f); f3 = fmaxf(f3, 0.f);
            f4 = fmaxf(f4, 0.f); f5 = fmaxf(f5, 0.f);
            f6 = fmaxf(f6, 0.f); f7 = fmaxf(f7, 0.f);
          }
          a[0] = (short)f2bf(f0); a[1] = (short)f2bf(f1);
          a[2] = (short)f2bf(f2); a[3] = (short)f2bf(f3);
          a[4] = (short)f2bf(f4); a[5] = (short)f2bf(f5);
          a[6] = (short)f2bf(f6); a[7] = (short)f2bf(f7);
        } else {
          a = *(const bf16x8*)&u;
        }
      } else {
        const float* xp = (const float*)Xv + (size_t)grow * K + kbase;
        float4 xa = *(const float4*)xp;
        float4 xb = *(const float4*)(xp + 4);
        a[0] = (short)f2bf(xa.x); a[1] = (short)f2bf(xa.y);
        a[2] = (short)f2bf(xa.z); a[3] = (short)f2bf(xa.w);
        a[4] = (short)f2bf(xb.x); a[5] = (short)f2bf(xb.y);
        a[6] = (short)f2bf(xb.z); a[7] = (short)f2bf(xb.w);
      }
    }
    bf16x8 b0 = *(const bf16x8*)(wt + (0 + lm) * K + kbase);
    bf16x8 b1 = *(const bf16x8*)(wt + (16 + lm) * K + kbase);
    bf16x8 b2 = *(const bf16x8*)(wt + (32 + lm) * K + kbase);
    bf16x8 b3 = *(const bf16x8*)(wt + (48 + lm) * K + kbase);
    acc0 = __builtin_amdgcn_mfma_f32_16x16x32_bf16(a, b0, acc0, 0, 0, 0);
    acc1 = __builtin_amdgcn_mfma_f32_16x16x32_bf16(a, b1, acc1, 0, 0, 0);
    acc2 = __builtin_amdgcn_mfma_f32_16x16x32_bf16(a, b2, acc2, 0, 0, 0);
    acc3 = __builtin_amdgcn_mfma_f32_16x16x32_bf16(a, b3, acc3, 0, 0, 0);
  }

#pragma unroll
  for (int r = 0; r < 4; ++r) {
    int rr = wv * 16 + lq * 4 + r;
    redo[rr * 65 + lm] = acc0[r];
    redo[rr * 65 + 16 + lm] = acc1[r];
    redo[rr * 65 + 32 + lm] = acc2[r];
    redo[rr * 65 + 48 + lm] = acc3[r];
  }
  __syncthreads();
  {
    int r = tid >> 2;
    int cq = (tid & 3) * 16;
    int gr = rowbase + r;
    if (gr < nrows) {
      float dn = dinv[gr];
      const float* sp = &redo[r * 65 + cq];
      unsigned p[8];
#pragma unroll
      for (int i = 0; i < 8; ++i)
        p[i] = f2bf(sp[2 * i] * dn) | (f2bf(sp[2 * i + 1] * dn) << 16);
      char* ob = (char*)out + ((size_t)gr * 64 + cq) * 2;
      *(uint4*)ob = make_uint4(p[0], p[1], p[2], p[3]);
      *(uint4*)(ob + 16) = make_uint4(p[4], p[5], p[6], p[7]);
    }
  }
}

// ---------------- aggregation: src-quartile phased ----------------
// Each 16-lane group owns 4 consecutive nodes with fp32 register accumulators.
// The grid sweeps src-quartiles q=0..3 in order (rp4 gives per-node quartile
// segment bounds) so the concurrent gather working set is 25K rows = 3.2 MB,
// which fits the 4 MB per-XCD L2 -> capacity misses on hs become L2 hits.
// All ~1563 blocks are co-resident (6252 waves <= 8192 slots), keeping the
// phases naturally aligned without a grid sync.
// POOL=true (layer 3): skip the global out-write entirely and fuse raw
// graph pooling (sum + count per graph) via block-local LDS; BN3 is affine
// and commutes with the mean, so it's applied in classify_k from sums.

template <bool POOL>
__global__ __launch_bounds__(256) void agg_k(
    const ushort_t* __restrict__ hs, const float* __restrict__ dinv,
    const int* __restrict__ rp4, const int* __restrict__ csr,
    const float* __restrict__ bias, ushort_t* __restrict__ out,
    float* __restrict__ sums, const int* __restrict__ batch,
    float* __restrict__ psum, float* __restrict__ pcnt) {
  const int tid = threadIdx.x;
  const int w = tid >> 6;
  const int lane = tid & 63;
  const int g = lane >> 4;     // node slot within wave
  const int q = lane & 15;     // feature quad
  const char* hb = (const char*)hs;
  char* ob = (char*)out;
  const int qo = q << 3;

  __shared__ float rs[16][64];
  __shared__ float rs2[16][64];
  __shared__ float pl[POOL ? 64 * 64 : 1];
  __shared__ float pcl[POOL ? 64 : 1];
  if (POOL) {
    for (int i = tid; i < 64 * 64; i += 256) pl[i] = 0.f;
    if (tid < 64) pcl[tid] = 0.f;
    __syncthreads();
  }

  const int nb = blockIdx.x * 64 + (w * 4 + g) * 4;  // first of 4 nodes

  int4 rp[4];
  int en[4];
#pragma unroll
  for (int i = 0; i < 4; ++i) {
    int n = nb + i;
    if (n < N_NODES) {
      rp[i] = *(const int4*)(rp4 + 4 * n);
      en[i] = rp4[4 * n + 4];
    } else {
      rp[i] = make_int4(0, 0, 0, 0);
      en[i] = 0;
    }
  }
  float4 bval = *(const float4*)(bias + q * 4);
  float4 acc[4];
#pragma unroll
  for (int i = 0; i < 4; ++i) acc[i] = make_float4(0.f, 0.f, 0.f, 0.f);

#define GV1(E, A) { uint2 v_ = *(const uint2*)(hb + (size_t)(unsigned)(E) + qo); \
    A.x += bflo(v_.x); A.y += bfhi(v_.x); A.z += bflo(v_.y); A.w += bfhi(v_.y); }

  for (int p = 0; p < 4; ++p) {
#pragma unroll
    for (int i = 0; i < 4; ++i) {
      int lo = (p == 0) ? rp[i].x : (p == 1) ? rp[i].y : (p == 2) ? rp[i].z : rp[i].w;
      int hi = (p == 3) ? en[i] : ((p == 0) ? rp[i].y : (p == 1) ? rp[i].z : rp[i].w);
      float4 a4 = acc[i];
      int jj = lo;
      for (; jj + 8 <= hi; jj += 8) {
        int e0 = csr[jj], e1 = csr[jj + 1], e2 = csr[jj + 2], e3 = csr[jj + 3];
        int e4 = csr[jj + 4], e5 = csr[jj + 5], e6 = csr[jj + 6], e7 = csr[jj + 7];
        uint2 v0 = *(const uint2*)(hb + (size_t)(unsigned)e0 + qo);
        uint2 v1 = *(const uint2*)(hb + (size_t)(unsigned)e1 + qo);
        uint2 v2 = *(const uint2*)(hb + (size_t)(unsigned)e2 + qo);
        uint2 v3 = *(const uint2*)(hb + (size_t)(unsigned)e3 + qo);
        uint2 v4 = *(const uint2*)(hb + (size_t)(unsigned)e4 + qo);
        uint2 v5 = *(const uint2*)(hb + (size_t)(unsigned)e5 + qo);
        uint2 v6 = *(const uint2*)(hb + (size_t)(unsigned)e6 + qo);
        uint2 v7 = *(const uint2*)(hb + (size_t)(unsigned)e7 + qo);
        a4.x += bflo(v0.x); a4.y += bfhi(v0.x); a4.z += bflo(v0.y); a4.w += bfhi(v0.y);
        a4.x += bflo(v1.x); a4.y += bfhi(v1.x); a4.z += bflo(v1.y); a4.w += bfhi(v1.y);
        a4.x += bflo(v2.x); a4.y += bfhi(v2.x); a4.z += bflo(v2.y); a4.w += bfhi(v2.y);
        a4.x += bflo(v3.x); a4.y += bfhi(v3.x); a4.z += bflo(v3.y); a4.w += bfhi(v3.y);
        a4.x += bflo(v4.x); a4.y += bfhi(v4.x); a4.z += bflo(v4.y); a4.w += bfhi(v4.y);
        a4.x += bflo(v5.x); a4.y += bfhi(v5.x); a4.z += bflo(v5.y); a4.w += bfhi(v5.y);
        a4.x += bflo(v6.x); a4.y += bfhi(v6.x); a4.z += bflo(v6.y); a4.w += bfhi(v6.y);
        a4.x += bflo(v7.x); a4.y += bfhi(v7.x); a4.z += bflo(v7.y); a4.w += bfhi(v7.y);
      }
      if (jj + 4 <= hi) {
        int e0 = csr[jj], e1 = csr[jj + 1], e2 = csr[jj + 2], e3 = csr[jj + 3];
        uint2 v0 = *(const uint2*)(hb + (size_t)(unsigned)e0 + qo);
        uint2 v1 = *(const uint2*)(hb + (size_t)(unsigned)e1 + qo);
        uint2 v2 = *(const uint2*)(hb + (size_t)(unsigned)e2 + qo);
        uint2 v3 = *(const uint2*)(hb + (size_t)(unsigned)e3 + qo);
        a4.x += bflo(v0.x); a4.y += bfhi(v0.x); a4.z += bflo(v0.y); a4.w += bfhi(v0.y);
        a4.x += bflo(v1.x); a4.y += bfhi(v1.x); a4.z += bflo(v1.y); a4.w += bfhi(v1.y);
        a4.x += bflo(v2.x); a4.y += bfhi(v2.x); a4.z += bflo(v2.y); a4.w += bfhi(v2.y);
        a4.x += bflo(v3.x); a4.y += bfhi(v3.x); a4.z += bflo(v3.y); a4.w += bfhi(v3.y);
        jj += 4;
      }
      if (jj + 2 <= hi) {
        int e0 = csr[jj], e1 = csr[jj + 1];
        uint2 v0 = *(const uint2*)(hb + (size_t)(unsigned)e0 + qo);
        uint2 v1 = *(const uint2*)(hb + (size_t)(unsigned)e1 + qo);
        a4.x += bflo(v0.x); a4.y += bfhi(v0.x); a4.z += bflo(v0.y); a4.w += bfhi(v0.y);
        a4.x += bflo(v1.x); a4.y += bfhi(v1.x); a4.z += bflo(v1.y); a4.w += bfhi(v1.y);
        jj += 2;
      }
      if (jj < hi) {
        GV1(csr[jj], a4)
      }
      acc[i] = a4;
    }
  }
#undef GV1

  float4 s = make_float4(0.f, 0.f, 0.f, 0.f);
  float4 s2 = make_float4(0.f, 0.f, 0.f, 0.f);
  int curg = -1, pcount = 0;
  float4 pacc = make_float4(0.f, 0.f, 0.f, 0.f);
#pragma unroll
  for (int i = 0; i < 4; ++i) {
    int n = nb + i;
    if (n < N_NODES) {
      uint2 su = *(const uint2*)(hb + ((size_t)n << 7) + qo);
      float dn = dinv[n];
      float4 a;
      a.x = (acc[i].x + bflo(su.x)) * dn + bval.x;
      a.y = (acc[i].y + bfhi(su.x)) * dn + bval.y;
      a.z = (acc[i].z + bflo(su.y)) * dn + bval.z;
      a.w = (acc[i].w + bfhi(su.y)) * dn + bval.w;
      if (!POOL) {
        uint2 o;
        o.x = f2bf(a.x) | (f2bf(a.y) << 16);
        o.y = f2bf(a.z) | (f2bf(a.w) << 16);
        *(uint2*)(ob + ((size_t)n << 7) + qo) = o;
      } else {
        int gi = batch[n];  // uniform across the 16-lane group
        if (gi != curg) {
          if (pcount) {
            atomicAdd(&pl[curg * 64 + (q << 2)], pacc.x);
            atomicAdd(&pl[curg * 64 + (q << 2) + 1], pacc.y);
            atomicAdd(&pl[curg * 64 + (q << 2) + 2], pacc.z);
            atomicAdd(&pl[curg * 64 + (q << 2) + 3], pacc.w);
            if (q == 0) atomicAdd(&pcl[curg], (float)pcount);
          }
          curg = gi;
          pacc = a;
          pcount = 1;
        } else {
          pacc.x += a.x; pacc.y += a.y; pacc.z += a.z; pacc.w += a.w;
          pcount++;
        }
      }
      s.x += a.x; s.y += a.y; s.z += a.z; s.w += a.w;
      s2.x += a.x * a.x; s2.y += a.y * a.y;
      s2.z += a.z * a.z; s2.w += a.w * a.w;
    }
  }
  if (POOL && pcount) {
    atomicAdd(&pl[curg * 64 + (q << 2)], pacc.x);
    atomicAdd(&pl[curg * 64 + (q << 2) + 1], pacc.y);
    atomicAdd(&pl[curg * 64 + (q << 2) + 2], pacc.z);
    atomicAdd(&pl[curg * 64 + (q << 2) + 3], pacc.w);
    if (q == 0) atomicAdd(&pcl[curg], (float)pcount);
  }

  *(float4*)(&rs[w * 4 + g][q * 4]) = s;
  *(float4*)(&rs2[w * 4 + g][q * 4]) = s2;
  __syncthreads();
  int c = tid & 63;
  int r0_ = tid >> 6;
  float a = rs[r0_][c] + rs[r0_ + 4][c] + rs[r0_ + 8][c] + rs[r0_ + 12][c];
  float a2 = rs2[r0_][c] + rs2[r0_ + 4][c] + rs2[r0_ + 8][c] + rs2[r0_ + 12][c];
  __syncthreads();
  rs[r0_][c] = a;
  rs2[r0_][c] = a2;
  __syncthreads();
  if (r0_ == 0) {
    atomicAdd(&sums[c], rs[0][c] + rs[1][c] + rs[2][c] + rs[3][c]);
    atomicAdd(&sums[64 + c], rs2[0][c] + rs2[1][c] + rs2[2][c] + rs2[3][c]);
  }
  if (POOL) {
    for (int idx = tid; idx < 64 * 64; idx += 256) {
      int gi = idx >> 6;
      if (pcl[gi] != 0.f) atomicAdd(&psum[idx], pl[idx]);
    }
    if (tid < 64 && pcl[tid] != 0.f) atomicAdd(&pcnt[tid], pcl[tid]);
  }
}

// ---------------- centroid classifier (BN3 affine applied here) ----------------

__global__ void classify_k(const float* __restrict__ psum, const float* __restrict__ pcnt,
                           const float* __restrict__ sums, const float* __restrict__ gamma,
                           const float* __restrict__ beta,
                           const float* __restrict__ cg_, const float* __restrict__ cm,
                           const float* __restrict__ temp, float* __restrict__ out) {
  int g = blockIdx.x;
  int t = threadIdx.x;
  __shared__ float emb[64];
  __shared__ float dist[208];
  if (t < 64) {
    float m = sums[t] / (float)N_NODES;
    float v = sums[64 + t] / (float)N_NODES - m * m;
    float sc = gamma[t] * rsqrtf(v + BN_EPS);
    float sh = beta[t] - m * sc;
    // mean(BN(a)) = sc*mean(a) + sh  (affine commutes with the mean)
    emb[t] = psum[g * 64 + t] / fmaxf(pcnt[g], 1.0f) * sc + sh;
  }
  __syncthreads();
  if (t < 197) {
    const float* C = (t < 5) ? (cg_ + t * 64) : (cm + (t - 5) * 64);
    float d = 0.f;
#pragma unroll 8
    for (int k = 0; k < 64; ++k) {
      float df = emb[k] - C[k];
      d += df * df;
    }
    dist[t] = d;
  }
  __syncthreads();
  float tv = temp[0];
  if (t == 64) {
    float m = dist[0];
    for (int j = 1; j < 5; ++j) m = fminf(m, dist[j]);
    out[g * 65] = -m / tv;
  }
  if (t < 64) {
    float m = fminf(dist[5 + t * 3], fminf(dist[5 + t * 3 + 1], dist[5 + t * 3 + 2]));
    out[g * 65 + 1 + t] = -m / tv;
  }
}

// ---------------- launch ----------------

extern "C" void kernel_launch(void* const* d_in, const int* in_sizes, int n_in,
                              void* d_out, int out_size, void* d_ws, size_t ws_size,
                              hipStream_t stream) {
  const float* x   = (const float*)d_in[0];
  const int* ei    = (const int*)d_in[1];
  const int* batch = (const int*)d_in[2];
  const float* W1 = (const float*)d_in[3];  const float* b1 = (const float*)d_in[4];
  const float* g1 = (const float*)d_in[5];  const float* be1 = (const float*)d_in[6];
  const float* W2 = (const float*)d_in[7];  const float* b2 = (const float*)d_in[8];
  const float* g2 = (const float*)d_in[9];  const float* be2 = (const float*)d_in[10];
  const float* W3 = (const float*)d_in[11]; const float* b3 = (const float*)d_in[12];
  const float* g3 = (const float*)d_in[13]; const float* be3 = (const float*)d_in[14];
  const float* cg_ = (const float*)d_in[15];
  const float* cm = (const float*)d_in[16];
  const float* temp = (const float*)d_in[17];
  float* out = (float*)d_out;

  char* ws = (char*)d_ws;
  size_t off = 0;
  auto alloc = [&](size_t bytes) -> void* {
    void* p = ws + off;
    off = (off + bytes + 255) & ~(size_t)255;
    return p;
  };
  // zero-init block first -> single memset
  int* gh        = (int*)alloc((size_t)NPB * 4);
  float* sumsAll = (float*)alloc(3 * 128 * 4);
  float* psum    = (float*)alloc(64 * 64 * 4);
  float* pcnt    = (float*)alloc(64 * 4);
  size_t zero_end = off;
  int* boff      = (int*)alloc((size_t)(NPB + 1) * 4);
  int* gcur      = (int*)alloc((size_t)NPB * 4);
  unsigned* tmp  = (unsigned*)alloc((size_t)N_EDGES * 4);
  int* csr       = (int*)alloc((size_t)N_EDGES * 4);
  int* rp4       = (int*)alloc((size_t)(4 * N_NODES + 1) * 4);
  float* dinv    = (float*)alloc((size_t)N_NODES * 4);
  ushort_t* hA   = (ushort_t*)alloc((size_t)N_NODES * 64 * 2);  // bf16 hs
  ushort_t* hB   = (ushort_t*)alloc((size_t)N_NODES * 64 * 2);  // bf16 h (pre-BN)

  hipMemsetAsync(ws, 0, zero_end, stream);

  const int NB_GEMM = (N_NODES + 63) / 64;   // 1563

  // CSR build
  ghist_k<<<512, 256, 0, stream>>>(ei, gh);
  gscan_k<<<1, 256, 0, stream>>>(gh, boff, gcur);
  part_k<<<PART_BLOCKS, 512, 0, stream>>>(ei, gcur, tmp);
  bwork_k<<<NPB, 512, 0, stream>>>(tmp, boff, rp4, dinv, csr);

  // layer 1 (MFMA, fp32 X -> bf16 frags)
  gemm_k<IN_DIM, false, false, false><<<NB_GEMM, 256, 0, stream>>>(x, W1, nullptr, nullptr, nullptr, dinv, hA, N_NODES);
  agg_k<false><<<NB_AGG, 256, 0, stream>>>(hA, dinv, rp4, csr, b1, hB, sumsAll, nullptr, nullptr, nullptr);

  // layer 2 (BN1+ReLU inline from sums, bf16 input)
  gemm_k<HID, true, true, true><<<NB_GEMM, 256, 0, stream>>>(hB, W2, sumsAll, g1, be1, dinv, hA, N_NODES);
  agg_k<false><<<NB_AGG, 256, 0, stream>>>(hA, dinv, rp4, csr, b2, hB, sumsAll + 128, nullptr, nullptr, nullptr);

  // layer 3 (BN2+ReLU inline from sums, bf16 input); agg fuses raw pooling
  gemm_k<HID, true, true, true><<<NB_GEMM, 256, 0, stream>>>(hB, W3, sumsAll + 128, g2, be2, dinv, hA, N_NODES);
  agg_k<true><<<NB_AGG, 256, 0, stream>>>(hA, dinv, rp4, csr, b3, nullptr, sumsAll + 256, batch, psum, pcnt);

  // classify (BN3 affine inline from sums)
  classify_k<<<N_GRAPHS, 256, 0, stream>>>(psum, pcnt, sumsAll + 256, g3, be3, cg_, cm, temp, out);
}

// Round 2
// 524.868 us; speedup vs baseline: 1.2327x; 1.2327x over previous
//
#include <hip/hip_runtime.h>
#include <math.h>

#define N_NODES 100000
#define N_EDGES 3200000
#define N_GRAPHS 64
#define IN_DIM 128
#define HID 64
#define BN_EPS 1e-5f

#define PSHIFT 9
#define PBS 512
#define NPB ((N_NODES + PBS - 1) / PBS)  // 196
#define PART_BLOCKS 256
#define CHUNK_E (N_EDGES / PART_BLOCKS)  // 12500 (multiple of 4)

#define QBOUND 25000
#define NB_AGG ((N_NODES + 63) / 64)  // 1563: 16 groups/block x 4 nodes/group

typedef unsigned short ushort_t;
typedef __attribute__((ext_vector_type(8))) short bf16x8;
typedef __attribute__((ext_vector_type(4))) float f32x4;

__device__ __forceinline__ float bflo(unsigned u) { return __uint_as_float(u << 16); }
__device__ __forceinline__ float bfhi(unsigned u) { return __uint_as_float(u & 0xFFFF0000u); }
__device__ __forceinline__ float bfu(ushort_t u) { return __uint_as_float((unsigned)u << 16); }
__device__ __forceinline__ unsigned f2bf(float f) {  // RNE
  unsigned u = __float_as_uint(f);
  return (u + 0x7FFFu + ((u >> 16) & 1u)) >> 16;
}

// ---------------- CSR build: two-level bucket sort, int4-vectorized ----------------

__global__ __launch_bounds__(256) void ghist_k(const int* __restrict__ ei,
                                               int* __restrict__ gh) {
  __shared__ int h[NPB];
  for (int i = threadIdx.x; i < NPB; i += 256) h[i] = 0;
  __syncthreads();
  const int4* d4 = (const int4*)(ei + N_EDGES);
  int n4 = N_EDGES / 4;
  int stride = gridDim.x * 256;
  for (int i = blockIdx.x * 256 + threadIdx.x; i < n4; i += stride) {
    int4 d = d4[i];
    atomicAdd(&h[d.x >> PSHIFT], 1);
    atomicAdd(&h[d.y >> PSHIFT], 1);
    atomicAdd(&h[d.z >> PSHIFT], 1);
    atomicAdd(&h[d.w >> PSHIFT], 1);
  }
  __syncthreads();
  for (int i = threadIdx.x; i < NPB; i += 256) {
    int v = h[i];
    if (v) atomicAdd(&gh[i], v);
  }
}

__global__ __launch_bounds__(256) void gscan_k(const int* __restrict__ gh,
                                               int* __restrict__ boff,
                                               int* __restrict__ gcur) {
  __shared__ int sa[256], sb[256];
  int t = threadIdx.x;
  int v = (t < NPB) ? gh[t] : 0;
  sa[t] = v;
  __syncthreads();
  int* src = sa; int* dst = sb;
  for (int o = 1; o < 256; o <<= 1) {
    dst[t] = src[t] + ((t >= o) ? src[t - o] : 0);
    __syncthreads();
    int* tmp = src; src = dst; dst = tmp;
  }
  if (t < NPB) {
    int excl = src[t] - v;
    boff[t] = excl;
    gcur[t] = excl;
    if (t == NPB - 1) boff[NPB] = src[t];
  }
}

__global__ __launch_bounds__(512) void part_k(const int* __restrict__ ei,
                                              int* __restrict__ gcur,
                                              unsigned* __restrict__ tmp) {
  __shared__ int lh[NPB];
  __shared__ int lcur[NPB];
  int t = threadIdx.x;
  for (int i = t; i < NPB; i += 512) lh[i] = 0;
  __syncthreads();
  int q0 = blockIdx.x * (CHUNK_E / 4);
  int q1 = q0 + CHUNK_E / 4;
  const int4* d4 = (const int4*)(ei + N_EDGES);
  const int4* s4 = (const int4*)ei;
  for (int i = q0 + t; i < q1; i += 512) {
    int4 d = d4[i];
    atomicAdd(&lh[d.x >> PSHIFT], 1);
    atomicAdd(&lh[d.y >> PSHIFT], 1);
    atomicAdd(&lh[d.z >> PSHIFT], 1);
    atomicAdd(&lh[d.w >> PSHIFT], 1);
  }
  __syncthreads();
  for (int i = t; i < NPB; i += 512) {
    int v = lh[i];
    lcur[i] = v ? atomicAdd(&gcur[i], v) : 0;
  }
  __syncthreads();
  for (int i = q0 + t; i < q1; i += 512) {
    int4 d = d4[i];
    int4 s = s4[i];
    int b0 = d.x >> PSHIFT, b1 = d.y >> PSHIFT, b2 = d.z >> PSHIFT, b3 = d.w >> PSHIFT;
    int p0 = atomicAdd(&lcur[b0], 1);
    int p1 = atomicAdd(&lcur[b1], 1);
    int p2 = atomicAdd(&lcur[b2], 1);
    int p3 = atomicAdd(&lcur[b3], 1);
    tmp[p0] = ((unsigned)(d.x & (PBS - 1)) << 17) | (unsigned)s.x;
    tmp[p1] = ((unsigned)(d.y & (PBS - 1)) << 17) | (unsigned)s.y;
    tmp[p2] = ((unsigned)(d.z & (PBS - 1)) << 17) | (unsigned)s.z;
    tmp[p3] = ((unsigned)(d.w & (PBS - 1)) << 17) | (unsigned)s.w;
  }
}

// fused per-bucket: histogram per (node, src-quartile) -> rp4/dinv -> place
// rp4[4n+k] = start of node n's src-quartile-k segment (quartile-sorted CSR)
__global__ __launch_bounds__(512) void bwork_k(
    const unsigned* __restrict__ tmp, const int* __restrict__ boff,
    int* __restrict__ rp4, float* __restrict__ dinv, int* __restrict__ csr) {
  int b = blockIdx.x;
  int base = boff[b], end = boff[b + 1];
  int t = threadIdx.x;
  __shared__ int cnt[PBS * 4];
  __shared__ int cur[PBS * 4];
  __shared__ int sa[PBS], sb[PBS];
  for (int i = t; i < PBS * 4; i += 512) cnt[i] = 0;
  __syncthreads();
  int a0 = (base + 3) & ~3;
  int a1 = end & ~3;
  if (a1 < a0) { a0 = end; a1 = end; }
  const uint4* t4 = (const uint4*)tmp;
#define HIST1(U) { unsigned u_ = (U); int nl_ = u_ >> 17; int s_ = u_ & 0x1FFFF; \
    int qq_ = (s_ >= QBOUND) + (s_ >= 2*QBOUND) + (s_ >= 3*QBOUND); \
    atomicAdd(&cnt[nl_ * 4 + qq_], 1); }
  if (base + t < a0) HIST1(tmp[base + t]);
  for (int i = a0 / 4 + t; i < a1 / 4; i += 512) {
    uint4 u = t4[i];
    HIST1(u.x) HIST1(u.y) HIST1(u.z) HIST1(u.w)
  }
  if (a1 + t < end) HIST1(tmp[a1 + t]);
#undef HIST1
  __syncthreads();
  int c0 = cnt[t * 4], c1 = cnt[t * 4 + 1], c2 = cnt[t * 4 + 2], c3 = cnt[t * 4 + 3];
  int tsum = c0 + c1 + c2 + c3;
  sa[t] = tsum;
  __syncthreads();
  int* src_ = sa; int* dst_ = sb;
  for (int o = 1; o < PBS; o <<= 1) {
    dst_[t] = src_[t] + ((t >= o) ? src_[t - o] : 0);
    __syncthreads();
    int* z = src_; src_ = dst_; dst_ = z;
  }
  int nb = src_[t] - tsum;
  int o0 = nb, o1 = nb + c0, o2 = nb + c0 + c1, o3 = nb + c0 + c1 + c2;
  cur[t * 4] = o0; cur[t * 4 + 1] = o1; cur[t * 4 + 2] = o2; cur[t * 4 + 3] = o3;
  int n = b * PBS + t;
  if (n < N_NODES) {
    rp4[4 * n] = base + o0;
    rp4[4 * n + 1] = base + o1;
    rp4[4 * n + 2] = base + o2;
    rp4[4 * n + 3] = base + o3;
    dinv[n] = rsqrtf((float)(tsum + 1));  // +1 self loop
    if (n == N_NODES - 1) rp4[4 * N_NODES] = base + nb + tsum;
  }
  __syncthreads();
#define PLACE1(U) { unsigned u_ = (U); int nl_ = u_ >> 17; int s_ = u_ & 0x1FFFF; \
    int qq_ = (s_ >= QBOUND) + (s_ >= 2*QBOUND) + (s_ >= 3*QBOUND); \
    int p_ = atomicAdd(&cur[nl_ * 4 + qq_], 1); \
    csr[base + p_] = s_ << 7; }
  if (base + t < a0) PLACE1(tmp[base + t]);
  for (int i = a0 / 4 + t; i < a1 / 4; i += 512) {
    uint4 u = t4[i];
    PLACE1(u.x) PLACE1(u.y) PLACE1(u.z) PLACE1(u.w)
  }
  if (a1 + t < end) PLACE1(tmp[a1 + t]);
#undef PLACE1
}

// ---------------- MFMA GEMM: hs[n][c] = dinv[n] * (BN(X)[n] @ W)[c] -> bf16 ----------------

template <int K, bool XBF16, bool APPLY, bool RELU>
__global__ __launch_bounds__(256) void gemm_k(
    const void* __restrict__ Xv, const float* __restrict__ W,
    const float* __restrict__ sums, const float* __restrict__ gamma,
    const float* __restrict__ beta, const float* __restrict__ dinv,
    ushort_t* __restrict__ out, int nrows) {
  __shared__ ushort_t wt[64 * K];   // wt[n][k] bf16
  __shared__ float scs[128], shs[128];
  __shared__ float redo[64 * 65];   // D repack, padded
  const int tid = threadIdx.x;
  const int wv = tid >> 6;
  const int lane = tid & 63;
  const int lm = lane & 15;
  const int lq = lane >> 4;

  for (int idx = tid; idx < K * 64; idx += 256) {
    int k = idx >> 6, c = idx & 63;      // W[k][c]
    wt[c * K + k] = (ushort_t)f2bf(W[idx]);
  }
  if (APPLY) {
    for (int k = tid; k < K; k += 256) {
      float m = sums[k] / (float)N_NODES;
      float v = sums[64 + k] / (float)N_NODES - m * m;
      float s = gamma[k] * rsqrtf(v + BN_EPS);
      scs[k] = s;
      shs[k] = beta[k] - m * s;
    }
  }
  __syncthreads();

  const int rowbase = blockIdx.x * 64;
  const int grow = rowbase + wv * 16 + lm;
  const bool valid = grow < nrows;
  f32x4 acc0 = {0.f, 0.f, 0.f, 0.f};
  f32x4 acc1 = acc0, acc2 = acc0, acc3 = acc0;

#pragma unroll
  for (int k0 = 0; k0 < K; k0 += 32) {
    int kbase = k0 + lq * 8;
    bf16x8 a = {0, 0, 0, 0, 0, 0, 0, 0};
    if (valid) {
      if (XBF16) {
        uint4 u = *(const uint4*)((const char*)Xv + ((size_t)grow * 64 + kbase) * 2);
        if (APPLY) {
          float4 sc0 = *(const float4*)&scs[kbase];
          float4 sc1 = *(const float4*)&scs[kbase + 4];
          float4 sh0 = *(const float4*)&shs[kbase];
          float4 sh1 = *(const float4*)&shs[kbase + 4];
          float f0 = bflo(u.x) * sc0.x + sh0.x, f1 = bfhi(u.x) * sc0.y + sh0.y;
          float f2 = bflo(u.y) * sc0.z + sh0.z, f3 = bfhi(u.y) * sc0.w + sh0.w;
          float f4 = bflo(u.z) * sc1.x + sh1.x, f5 = bfhi(u.z) * sc1.y + sh1.y;
          float f6 = bflo(u.w) * sc1.z + sh1.z, f7 = bfhi(u.w) * sc1.w + sh1.w;
          if (RELU) {
            f0 = fmaxf(f0, 0.f); f1 = fmaxf(f1, 0.f);
            f2 = fmaxf(f2, 0.f); f3 = fmaxf(f3, 0.f);
            f4 = fmaxf(f4, 0.f); f5 = fmaxf(f5, 0.f);
            f6 = fmaxf(f6, 0.f); f7 = fmaxf(f7, 0.f);
          }
          a[0] = (short)f2bf(f0); a[1] = (short)f2bf(f1);
          a[2] = (short)f2bf(f2); a[3] = (short)f2bf(f3);
          a[4] = (short)f2bf(f4); a[5] = (short)f2bf(f5);
          a[6] = (short)f2bf(f6); a[7] = (short)f2bf(f7);
        } else {
          a = *(const bf16x8*)&u;
        }
      } else {
        const float* xp = (const float*)Xv + (size_t)grow * K + kbase;
        float4 xa = *(const float4*)xp;
        float4 xb = *(const float4*)(xp + 4);
        a[0] = (short)f2bf(xa.x); a[1] = (short)f2bf(xa.y);
        a[2] = (short)f2bf(xa.z); a[3] = (short)f2bf(xa.w);
        a[4] = (short)f2bf(xb.x); a[5] = (short)f2bf(xb.y);
        a[6] = (short)f2bf(xb.z); a[7] = (short)f2bf(xb.w);
      }
    }
    bf16x8 b0 = *(const bf16x8*)(wt + (0 + lm) * K + kbase);
    bf16x8 b1 = *(const bf16x8*)(wt + (16 + lm) * K + kbase);
    bf16x8 b2 = *(const bf16x8*)(wt + (32 + lm) * K + kbase);
    bf16x8 b3 = *(const bf16x8*)(wt + (48 + lm) * K + kbase);
    acc0 = __builtin_amdgcn_mfma_f32_16x16x32_bf16(a, b0, acc0, 0, 0, 0);
    acc1 = __builtin_amdgcn_mfma_f32_16x16x32_bf16(a, b1, acc1, 0, 0, 0);
    acc2 = __builtin_amdgcn_mfma_f32_16x16x32_bf16(a, b2, acc2, 0, 0, 0);
    acc3 = __builtin_amdgcn_mfma_f32_16x16x32_bf16(a, b3, acc3, 0, 0, 0);
  }

#pragma unroll
  for (int r = 0; r < 4; ++r) {
    int rr = wv * 16 + lq * 4 + r;
    redo[rr * 65 + lm] = acc0[r];
    redo[rr * 65 + 16 + lm] = acc1[r];
    redo[rr * 65 + 32 + lm] = acc2[r];
    redo[rr * 65 + 48 + lm] = acc3[r];
  }
  __syncthreads();
  {
    int r = tid >> 2;
    int cq = (tid & 3) * 16;
    int gr = rowbase + r;
    if (gr < nrows) {
      float dn = dinv[gr];
      const float* sp = &redo[r * 65 + cq];
      unsigned p[8];
#pragma unroll
      for (int i = 0; i < 8; ++i)
        p[i] = f2bf(sp[2 * i] * dn) | (f2bf(sp[2 * i + 1] * dn) << 16);
      char* ob = (char*)out + ((size_t)gr * 64 + cq) * 2;
      *(uint4*)ob = make_uint4(p[0], p[1], p[2], p[3]);
      *(uint4*)(ob + 16) = make_uint4(p[4], p[5], p[6], p[7]);
    }
  }
}

// ---------------- aggregation: src-quartile phased + 4-node interleaved pipeline ----------------
// Each 16-lane group owns 4 consecutive nodes (fp32 register accumulators).
// The grid sweeps src-quartiles p=0..3 so the concurrent gather working set is
// 25K rows = 3.2 MB < 4 MB per-XCD L2 (round-1: FETCH 157->103 MB, verified).
// Round-1 regression fix: within a phase, the four nodes' quartile segments are
// processed CONCURRENTLY (2 edges/node x 4 nodes = 8 gathers in flight), with
// the next iteration's 8 csr entries prefetched while the gathers are in
// flight. Length mismatch across nodes is handled by clamped csr indices
// (duplicate loads hit L1) + AND-masking gathered words to zero.
// POOL=true (layer 3): skip the global out-write and fuse raw graph pooling
// (sum + count per graph) via block-local LDS; BN3 affine applied in classify_k.

template <bool POOL>
__global__ __launch_bounds__(256) void agg_k(
    const ushort_t* __restrict__ hs, const float* __restrict__ dinv,
    const int* __restrict__ rp4, const int* __restrict__ csr,
    const float* __restrict__ bias, ushort_t* __restrict__ out,
    float* __restrict__ sums, const int* __restrict__ batch,
    float* __restrict__ psum, float* __restrict__ pcnt) {
  const int tid = threadIdx.x;
  const int w = tid >> 6;
  const int lane = tid & 63;
  const int g = lane >> 4;     // node-group slot within wave
  const int q = lane & 15;     // feature quad
  const char* hb = (const char*)hs;
  char* ob = (char*)out;
  const int qo = q << 3;

  __shared__ float rs[16][64];
  __shared__ float rs2[16][64];
  __shared__ float pl[POOL ? 64 * 64 : 1];
  __shared__ float pcl[POOL ? 64 : 1];
  if (POOL) {
    for (int i = tid; i < 64 * 64; i += 256) pl[i] = 0.f;
    if (tid < 64) pcl[tid] = 0.f;
    __syncthreads();
  }

  const int nb = blockIdx.x * 64 + (w * 4 + g) * 4;  // first of 4 nodes

  int4 rp[4];
  int en[4];
#pragma unroll
  for (int i = 0; i < 4; ++i) {
    int n = nb + i;
    if (n < N_NODES) {
      rp[i] = *(const int4*)(rp4 + 4 * n);
      en[i] = rp4[4 * n + 4];
    } else {
      rp[i] = make_int4(0, 0, 0, 0);
      en[i] = 0;
    }
  }
  float4 bval = *(const float4*)(bias + q * 4);
  float4 acc0 = make_float4(0.f, 0.f, 0.f, 0.f);
  float4 acc1 = acc0, acc2 = acc0, acc3 = acc0;

#define ACCV(A, V, M) { unsigned xm_ = (V).x & (M), ym_ = (V).y & (M); \
    A.x += bflo(xm_); A.y += bfhi(xm_); A.z += bflo(ym_); A.w += bfhi(ym_); }

#pragma unroll
  for (int p = 0; p < 4; ++p) {
    int j0 = (p == 0) ? rp[0].x : (p == 1) ? rp[0].y : (p == 2) ? rp[0].z : rp[0].w;
    int h0 = (p == 3) ? en[0] : ((p == 0) ? rp[0].y : (p == 1) ? rp[0].z : rp[0].w);
    int j1 = (p == 0) ? rp[1].x : (p == 1) ? rp[1].y : (p == 2) ? rp[1].z : rp[1].w;
    int h1 = (p == 3) ? en[1] : ((p == 0) ? rp[1].y : (p == 1) ? rp[1].z : rp[1].w);
    int j2 = (p == 0) ? rp[2].x : (p == 1) ? rp[2].y : (p == 2) ? rp[2].z : rp[2].w;
    int h2 = (p == 3) ? en[2] : ((p == 0) ? rp[2].y : (p == 1) ? rp[2].z : rp[2].w);
    int j3 = (p == 0) ? rp[3].x : (p == 1) ? rp[3].y : (p == 2) ? rp[3].z : rp[3].w;
    int h3 = (p == 3) ? en[3] : ((p == 0) ? rp[3].y : (p == 1) ? rp[3].z : rp[3].w);

    int mrem = max(max(h0 - j0, h1 - j1), max(h2 - j2, h3 - j3));
    int iters = (mrem + 1) >> 1;
    if (iters > 0) {
      // prologue: first csr batch (clamped indices; duplicates are L1 hits)
      int e00 = csr[j0     < h0 ? j0     : h0 - 1];
      int e01 = csr[j0 + 1 < h0 ? j0 + 1 : h0 - 1];
      int e10 = csr[j1     < h1 ? j1     : h1 - 1];
      int e11 = csr[j1 + 1 < h1 ? j1 + 1 : h1 - 1];
      int e20 = csr[j2     < h2 ? j2     : h2 - 1];
      int e21 = csr[j2 + 1 < h2 ? j2 + 1 : h2 - 1];
      int e30 = csr[j3     < h3 ? j3     : h3 - 1];
      int e31 = csr[j3 + 1 < h3 ? j3 + 1 : h3 - 1];
      for (int it = 0; it < iters; ++it) {
        // 8 gathers in flight
        uint2 v00 = *(const uint2*)(hb + (size_t)(unsigned)e00 + qo);
        uint2 v01 = *(const uint2*)(hb + (size_t)(unsigned)e01 + qo);
        uint2 v10 = *(const uint2*)(hb + (size_t)(unsigned)e10 + qo);
        uint2 v11 = *(const uint2*)(hb + (size_t)(unsigned)e11 + qo);
        uint2 v20 = *(const uint2*)(hb + (size_t)(unsigned)e20 + qo);
        uint2 v21 = *(const uint2*)(hb + (size_t)(unsigned)e21 + qo);
        uint2 v30 = *(const uint2*)(hb + (size_t)(unsigned)e30 + qo);
        uint2 v31 = *(const uint2*)(hb + (size_t)(unsigned)e31 + qo);
        unsigned m00 = (j0     < h0) ? 0xFFFFFFFFu : 0u;
        unsigned m01 = (j0 + 1 < h0) ? 0xFFFFFFFFu : 0u;
        unsigned m10 = (j1     < h1) ? 0xFFFFFFFFu : 0u;
        unsigned m11 = (j1 + 1 < h1) ? 0xFFFFFFFFu : 0u;
        unsigned m20 = (j2     < h2) ? 0xFFFFFFFFu : 0u;
        unsigned m21 = (j2 + 1 < h2) ? 0xFFFFFFFFu : 0u;
        unsigned m30 = (j3     < h3) ? 0xFFFFFFFFu : 0u;
        unsigned m31 = (j3 + 1 < h3) ? 0xFFFFFFFFu : 0u;
        j0 += 2; j1 += 2; j2 += 2; j3 += 2;
        // prefetch next csr batch while gathers are in flight
        e00 = csr[j0     < h0 ? j0     : h0 - 1];
        e01 = csr[j0 + 1 < h0 ? j0 + 1 : h0 - 1];
        e10 = csr[j1     < h1 ? j1     : h1 - 1];
        e11 = csr[j1 + 1 < h1 ? j1 + 1 : h1 - 1];
        e20 = csr[j2     < h2 ? j2     : h2 - 1];
        e21 = csr[j2 + 1 < h2 ? j2 + 1 : h2 - 1];
        e30 = csr[j3     < h3 ? j3     : h3 - 1];
        e31 = csr[j3 + 1 < h3 ? j3 + 1 : h3 - 1];
        // masked accumulate
        ACCV(acc0, v00, m00) ACCV(acc0, v01, m01)
        ACCV(acc1, v10, m10) ACCV(acc1, v11, m11)
        ACCV(acc2, v20, m20) ACCV(acc2, v21, m21)
        ACCV(acc3, v30, m30) ACCV(acc3, v31, m31)
      }
    }
  }
#undef ACCV

  float4 s = make_float4(0.f, 0.f, 0.f, 0.f);
  float4 s2 = make_float4(0.f, 0.f, 0.f, 0.f);
  int curg = -1, pcount = 0;
  float4 pacc = make_float4(0.f, 0.f, 0.f, 0.f);
#pragma unroll
  for (int i = 0; i < 4; ++i) {
    int n = nb + i;
    if (n < N_NODES) {
      float4 ai = (i == 0) ? acc0 : (i == 1) ? acc1 : (i == 2) ? acc2 : acc3;
      uint2 su = *(const uint2*)(hb + ((size_t)n << 7) + qo);
      float dn = dinv[n];
      float4 a;
      a.x = (ai.x + bflo(su.x)) * dn + bval.x;
      a.y = (ai.y + bfhi(su.x)) * dn + bval.y;
      a.z = (ai.z + bflo(su.y)) * dn + bval.z;
      a.w = (ai.w + bfhi(su.y)) * dn + bval.w;
      if (!POOL) {
        uint2 o;
        o.x = f2bf(a.x) | (f2bf(a.y) << 16);
        o.y = f2bf(a.z) | (f2bf(a.w) << 16);
        *(uint2*)(ob + ((size_t)n << 7) + qo) = o;
      } else {
        int gi = batch[n];  // uniform across the 16-lane group
        if (gi != curg) {
          if (pcount) {
            atomicAdd(&pl[curg * 64 + (q << 2)], pacc.x);
            atomicAdd(&pl[curg * 64 + (q << 2) + 1], pacc.y);
            atomicAdd(&pl[curg * 64 + (q << 2) + 2], pacc.z);
            atomicAdd(&pl[curg * 64 + (q << 2) + 3], pacc.w);
            if (q == 0) atomicAdd(&pcl[curg], (float)pcount);
          }
          curg = gi;
          pacc = a;
          pcount = 1;
        } else {
          pacc.x += a.x; pacc.y += a.y; pacc.z += a.z; pacc.w += a.w;
          pcount++;
        }
      }
      s.x += a.x; s.y += a.y; s.z += a.z; s.w += a.w;
      s2.x += a.x * a.x; s2.y += a.y * a.y;
      s2.z += a.z * a.z; s2.w += a.w * a.w;
    }
  }
  if (POOL && pcount) {
    atomicAdd(&pl[curg * 64 + (q << 2)], pacc.x);
    atomicAdd(&pl[curg * 64 + (q << 2) + 1], pacc.y);
    atomicAdd(&pl[curg * 64 + (q << 2) + 2], pacc.z);
    atomicAdd(&pl[curg * 64 + (q << 2) + 3], pacc.w);
    if (q == 0) atomicAdd(&pcl[curg], (float)pcount);
  }

  *(float4*)(&rs[w * 4 + g][q * 4]) = s;
  *(float4*)(&rs2[w * 4 + g][q * 4]) = s2;
  __syncthreads();
  int c = tid & 63;
  int r0_ = tid >> 6;
  float a = rs[r0_][c] + rs[r0_ + 4][c] + rs[r0_ + 8][c] + rs[r0_ + 12][c];
  float a2 = rs2[r0_][c] + rs2[r0_ + 4][c] + rs2[r0_ + 8][c] + rs2[r0_ + 12][c];
  __syncthreads();
  rs[r0_][c] = a;
  rs2[r0_][c] = a2;
  __syncthreads();
  if (r0_ == 0) {
    atomicAdd(&sums[c], rs[0][c] + rs[1][c] + rs[2][c] + rs[3][c]);
    atomicAdd(&sums[64 + c], rs2[0][c] + rs2[1][c] + rs2[2][c] + rs2[3][c]);
  }
  if (POOL) {
    for (int idx = tid; idx < 64 * 64; idx += 256) {
      int gi = idx >> 6;
      if (pcl[gi] != 0.f) atomicAdd(&psum[idx], pl[idx]);
    }
    if (tid < 64 && pcl[tid] != 0.f) atomicAdd(&pcnt[tid], pcl[tid]);
  }
}

// ---------------- centroid classifier (BN3 affine applied here) ----------------

__global__ void classify_k(const float* __restrict__ psum, const float* __restrict__ pcnt,
                           const float* __restrict__ sums, const float* __restrict__ gamma,
                           const float* __restrict__ beta,
                           const float* __restrict__ cg_, const float* __restrict__ cm,
                           const float* __restrict__ temp, float* __restrict__ out) {
  int g = blockIdx.x;
  int t = threadIdx.x;
  __shared__ float emb[64];
  __shared__ float dist[208];
  if (t < 64) {
    float m = sums[t] / (float)N_NODES;
    float v = sums[64 + t] / (float)N_NODES - m * m;
    float sc = gamma[t] * rsqrtf(v + BN_EPS);
    float sh = beta[t] - m * sc;
    // mean(BN(a)) = sc*mean(a) + sh  (affine commutes with the mean)
    emb[t] = psum[g * 64 + t] / fmaxf(pcnt[g], 1.0f) * sc + sh;
  }
  __syncthreads();
  if (t < 197) {
    const float* C = (t < 5) ? (cg_ + t * 64) : (cm + (t - 5) * 64);
    float d = 0.f;
#pragma unroll 8
    for (int k = 0; k < 64; ++k) {
      float df = emb[k] - C[k];
      d += df * df;
    }
    dist[t] = d;
  }
  __syncthreads();
  float tv = temp[0];
  if (t == 64) {
    float m = dist[0];
    for (int j = 1; j < 5; ++j) m = fminf(m, dist[j]);
    out[g * 65] = -m / tv;
  }
  if (t < 64) {
    float m = fminf(dist[5 + t * 3], fminf(dist[5 + t * 3 + 1], dist[5 + t * 3 + 2]));
    out[g * 65 + 1 + t] = -m / tv;
  }
}

// ---------------- launch ----------------

extern "C" void kernel_launch(void* const* d_in, const int* in_sizes, int n_in,
                              void* d_out, int out_size, void* d_ws, size_t ws_size,
                              hipStream_t stream) {
  const float* x   = (const float*)d_in[0];
  const int* ei    = (const int*)d_in[1];
  const int* batch = (const int*)d_in[2];
  const float* W1 = (const float*)d_in[3];  const float* b1 = (const float*)d_in[4];
  const float* g1 = (const float*)d_in[5];  const float* be1 = (const float*)d_in[6];
  const float* W2 = (const float*)d_in[7];  const float* b2 = (const float*)d_in[8];
  const float* g2 = (const float*)d_in[9];  const float* be2 = (const float*)d_in[10];
  const float* W3 = (const float*)d_in[11]; const float* b3 = (const float*)d_in[12];
  const float* g3 = (const float*)d_in[13]; const float* be3 = (const float*)d_in[14];
  const float* cg_ = (const float*)d_in[15];
  const float* cm = (const float*)d_in[16];
  const float* temp = (const float*)d_in[17];
  float* out = (float*)d_out;

  char* ws = (char*)d_ws;
  size_t off = 0;
  auto alloc = [&](size_t bytes) -> void* {
    void* p = ws + off;
    off = (off + bytes + 255) & ~(size_t)255;
    return p;
  };
  // zero-init block first -> single memset
  int* gh        = (int*)alloc((size_t)NPB * 4);
  float* sumsAll = (float*)alloc(3 * 128 * 4);
  float* psum    = (float*)alloc(64 * 64 * 4);
  float* pcnt    = (float*)alloc(64 * 4);
  size_t zero_end = off;
  int* boff      = (int*)alloc((size_t)(NPB + 1) * 4);
  int* gcur      = (int*)alloc((size_t)NPB * 4);
  unsigned* tmp  = (unsigned*)alloc((size_t)N_EDGES * 4);
  int* csr       = (int*)alloc((size_t)N_EDGES * 4);
  int* rp4       = (int*)alloc((size_t)(4 * N_NODES + 1) * 4);
  float* dinv    = (float*)alloc((size_t)N_NODES * 4);
  ushort_t* hA   = (ushort_t*)alloc((size_t)N_NODES * 64 * 2);  // bf16 hs
  ushort_t* hB   = (ushort_t*)alloc((size_t)N_NODES * 64 * 2);  // bf16 h (pre-BN)

  hipMemsetAsync(ws, 0, zero_end, stream);

  const int NB_GEMM = (N_NODES + 63) / 64;   // 1563

  // CSR build
  ghist_k<<<512, 256, 0, stream>>>(ei, gh);
  gscan_k<<<1, 256, 0, stream>>>(gh, boff, gcur);
  part_k<<<PART_BLOCKS, 512, 0, stream>>>(ei, gcur, tmp);
  bwork_k<<<NPB, 512, 0, stream>>>(tmp, boff, rp4, dinv, csr);

  // layer 1 (MFMA, fp32 X -> bf16 frags)
  gemm_k<IN_DIM, false, false, false><<<NB_GEMM, 256, 0, stream>>>(x, W1, nullptr, nullptr, nullptr, dinv, hA, N_NODES);
  agg_k<false><<<NB_AGG, 256, 0, stream>>>(hA, dinv, rp4, csr, b1, hB, sumsAll, nullptr, nullptr, nullptr);

  // layer 2 (BN1+ReLU inline from sums, bf16 input)
  gemm_k<HID, true, true, true><<<NB_GEMM, 256, 0, stream>>>(hB, W2, sumsAll, g1, be1, dinv, hA, N_NODES);
  agg_k<false><<<NB_AGG, 256, 0, stream>>>(hA, dinv, rp4, csr, b2, hB, sumsAll + 128, nullptr, nullptr, nullptr);

  // layer 3 (BN2+ReLU inline from sums, bf16 input); agg fuses raw pooling
  gemm_k<HID, true, true, true><<<NB_GEMM, 256, 0, stream>>>(hB, W3, sumsAll + 128, g2, be2, dinv, hA, N_NODES);
  agg_k<true><<<NB_AGG, 256, 0, stream>>>(hA, dinv, rp4, csr, b3, nullptr, sumsAll + 256, batch, psum, pcnt);

  // classify (BN3 affine inline from sums)
  classify_k<<<N_GRAPHS, 256, 0, stream>>>(psum, pcnt, sumsAll + 256, g3, be3, cg_, cm, temp, out);
}

// Round 3
// 512.777 us; speedup vs baseline: 1.2617x; 1.0236x over previous
//
#include <hip/hip_runtime.h>
#include <math.h>

#define N_NODES 100000
#define N_EDGES 3200000
#define N_GRAPHS 64
#define IN_DIM 128
#define HID 64
#define BN_EPS 1e-5f

#define PSHIFT 9
#define PBS 512
#define NPB ((N_NODES + PBS - 1) / PBS)  // 196
#define PART_BLOCKS 256
#define CHUNK_E (N_EDGES / PART_BLOCKS)  // 12500 (multiple of 4)

#define QBOUND 25000
#define NB_AGG ((N_NODES + 63) / 64)  // 1563: 16 groups/block x 4 nodes/group
#define SENT_OFF (N_NODES << 7)       // byte offset of zeroed sentinel row in hs

typedef unsigned short ushort_t;
typedef __attribute__((ext_vector_type(8))) short bf16x8;
typedef __attribute__((ext_vector_type(4))) float f32x4;

__device__ __forceinline__ float bflo(unsigned u) { return __uint_as_float(u << 16); }
__device__ __forceinline__ float bfhi(unsigned u) { return __uint_as_float(u & 0xFFFF0000u); }
__device__ __forceinline__ float bfu(ushort_t u) { return __uint_as_float((unsigned)u << 16); }
__device__ __forceinline__ unsigned f2bf(float f) {  // RNE
  unsigned u = __float_as_uint(f);
  return (u + 0x7FFFu + ((u >> 16) & 1u)) >> 16;
}

// ---------------- CSR build: two-level bucket sort, int4-vectorized ----------------

__global__ __launch_bounds__(256) void ghist_k(const int* __restrict__ ei,
                                               int* __restrict__ gh) {
  __shared__ int h[NPB];
  for (int i = threadIdx.x; i < NPB; i += 256) h[i] = 0;
  __syncthreads();
  const int4* d4 = (const int4*)(ei + N_EDGES);
  int n4 = N_EDGES / 4;
  int stride = gridDim.x * 256;
  for (int i = blockIdx.x * 256 + threadIdx.x; i < n4; i += stride) {
    int4 d = d4[i];
    atomicAdd(&h[d.x >> PSHIFT], 1);
    atomicAdd(&h[d.y >> PSHIFT], 1);
    atomicAdd(&h[d.z >> PSHIFT], 1);
    atomicAdd(&h[d.w >> PSHIFT], 1);
  }
  __syncthreads();
  for (int i = threadIdx.x; i < NPB; i += 256) {
    int v = h[i];
    if (v) atomicAdd(&gh[i], v);
  }
}

__global__ __launch_bounds__(256) void gscan_k(const int* __restrict__ gh,
                                               int* __restrict__ boff,
                                               int* __restrict__ gcur) {
  __shared__ int sa[256], sb[256];
  int t = threadIdx.x;
  int v = (t < NPB) ? gh[t] : 0;
  sa[t] = v;
  __syncthreads();
  int* src = sa; int* dst = sb;
  for (int o = 1; o < 256; o <<= 1) {
    dst[t] = src[t] + ((t >= o) ? src[t - o] : 0);
    __syncthreads();
    int* tmp = src; src = dst; dst = tmp;
  }
  if (t < NPB) {
    int excl = src[t] - v;
    boff[t] = excl;
    gcur[t] = excl;
    if (t == NPB - 1) boff[NPB] = src[t];
  }
}

__global__ __launch_bounds__(512) void part_k(const int* __restrict__ ei,
                                              int* __restrict__ gcur,
                                              unsigned* __restrict__ tmp) {
  __shared__ int lh[NPB];
  __shared__ int lcur[NPB];
  int t = threadIdx.x;
  for (int i = t; i < NPB; i += 512) lh[i] = 0;
  __syncthreads();
  int q0 = blockIdx.x * (CHUNK_E / 4);
  int q1 = q0 + CHUNK_E / 4;
  const int4* d4 = (const int4*)(ei + N_EDGES);
  const int4* s4 = (const int4*)ei;
  for (int i = q0 + t; i < q1; i += 512) {
    int4 d = d4[i];
    atomicAdd(&lh[d.x >> PSHIFT], 1);
    atomicAdd(&lh[d.y >> PSHIFT], 1);
    atomicAdd(&lh[d.z >> PSHIFT], 1);
    atomicAdd(&lh[d.w >> PSHIFT], 1);
  }
  __syncthreads();
  for (int i = t; i < NPB; i += 512) {
    int v = lh[i];
    lcur[i] = v ? atomicAdd(&gcur[i], v) : 0;
  }
  __syncthreads();
  for (int i = q0 + t; i < q1; i += 512) {
    int4 d = d4[i];
    int4 s = s4[i];
    int b0 = d.x >> PSHIFT, b1 = d.y >> PSHIFT, b2 = d.z >> PSHIFT, b3 = d.w >> PSHIFT;
    int p0 = atomicAdd(&lcur[b0], 1);
    int p1 = atomicAdd(&lcur[b1], 1);
    int p2 = atomicAdd(&lcur[b2], 1);
    int p3 = atomicAdd(&lcur[b3], 1);
    tmp[p0] = ((unsigned)(d.x & (PBS - 1)) << 17) | (unsigned)s.x;
    tmp[p1] = ((unsigned)(d.y & (PBS - 1)) << 17) | (unsigned)s.y;
    tmp[p2] = ((unsigned)(d.z & (PBS - 1)) << 17) | (unsigned)s.z;
    tmp[p3] = ((unsigned)(d.w & (PBS - 1)) << 17) | (unsigned)s.w;
  }
}

// fused per-bucket: histogram per (node, src-quartile) -> rp4/dinv -> place
// rp4[4n+k] = start of node n's src-quartile-k segment (quartile-sorted CSR)
__global__ __launch_bounds__(512) void bwork_k(
    const unsigned* __restrict__ tmp, const int* __restrict__ boff,
    int* __restrict__ rp4, float* __restrict__ dinv, int* __restrict__ csr) {
  int b = blockIdx.x;
  int base = boff[b], end = boff[b + 1];
  int t = threadIdx.x;
  __shared__ int cnt[PBS * 4];
  __shared__ int cur[PBS * 4];
  __shared__ int sa[PBS], sb[PBS];
  for (int i = t; i < PBS * 4; i += 512) cnt[i] = 0;
  __syncthreads();
  int a0 = (base + 3) & ~3;
  int a1 = end & ~3;
  if (a1 < a0) { a0 = end; a1 = end; }
  const uint4* t4 = (const uint4*)tmp;
#define HIST1(U) { unsigned u_ = (U); int nl_ = u_ >> 17; int s_ = u_ & 0x1FFFF; \
    int qq_ = (s_ >= QBOUND) + (s_ >= 2*QBOUND) + (s_ >= 3*QBOUND); \
    atomicAdd(&cnt[nl_ * 4 + qq_], 1); }
  if (base + t < a0) HIST1(tmp[base + t]);
  for (int i = a0 / 4 + t; i < a1 / 4; i += 512) {
    uint4 u = t4[i];
    HIST1(u.x) HIST1(u.y) HIST1(u.z) HIST1(u.w)
  }
  if (a1 + t < end) HIST1(tmp[a1 + t]);
#undef HIST1
  __syncthreads();
  int c0 = cnt[t * 4], c1 = cnt[t * 4 + 1], c2 = cnt[t * 4 + 2], c3 = cnt[t * 4 + 3];
  int tsum = c0 + c1 + c2 + c3;
  sa[t] = tsum;
  __syncthreads();
  int* src_ = sa; int* dst_ = sb;
  for (int o = 1; o < PBS; o <<= 1) {
    dst_[t] = src_[t] + ((t >= o) ? src_[t - o] : 0);
    __syncthreads();
    int* z = src_; src_ = dst_; dst_ = z;
  }
  int nb = src_[t] - tsum;
  int o0 = nb, o1 = nb + c0, o2 = nb + c0 + c1, o3 = nb + c0 + c1 + c2;
  cur[t * 4] = o0; cur[t * 4 + 1] = o1; cur[t * 4 + 2] = o2; cur[t * 4 + 3] = o3;
  int n = b * PBS + t;
  if (n < N_NODES) {
    rp4[4 * n] = base + o0;
    rp4[4 * n + 1] = base + o1;
    rp4[4 * n + 2] = base + o2;
    rp4[4 * n + 3] = base + o3;
    dinv[n] = rsqrtf((float)(tsum + 1));  // +1 self loop
    if (n == N_NODES - 1) rp4[4 * N_NODES] = base + nb + tsum;
  }
  __syncthreads();
#define PLACE1(U) { unsigned u_ = (U); int nl_ = u_ >> 17; int s_ = u_ & 0x1FFFF; \
    int qq_ = (s_ >= QBOUND) + (s_ >= 2*QBOUND) + (s_ >= 3*QBOUND); \
    int p_ = atomicAdd(&cur[nl_ * 4 + qq_], 1); \
    csr[base + p_] = s_ << 7; }
  if (base + t < a0) PLACE1(tmp[base + t]);
  for (int i = a0 / 4 + t; i < a1 / 4; i += 512) {
    uint4 u = t4[i];
    PLACE1(u.x) PLACE1(u.y) PLACE1(u.z) PLACE1(u.w)
  }
  if (a1 + t < end) PLACE1(tmp[a1 + t]);
#undef PLACE1
}

// ---------------- MFMA GEMM: hs[n][c] = dinv[n] * (BN(X)[n] @ W)[c] -> bf16 ----------------

template <int K, bool XBF16, bool APPLY, bool RELU>
__global__ __launch_bounds__(256) void gemm_k(
    const void* __restrict__ Xv, const float* __restrict__ W,
    const float* __restrict__ sums, const float* __restrict__ gamma,
    const float* __restrict__ beta, const float* __restrict__ dinv,
    ushort_t* __restrict__ out, int nrows) {
  __shared__ ushort_t wt[64 * K];   // wt[n][k] bf16
  __shared__ float scs[128], shs[128];
  __shared__ float redo[64 * 65];   // D repack, padded
  const int tid = threadIdx.x;
  const int wv = tid >> 6;
  const int lane = tid & 63;
  const int lm = lane & 15;
  const int lq = lane >> 4;

  for (int idx = tid; idx < K * 64; idx += 256) {
    int k = idx >> 6, c = idx & 63;      // W[k][c]
    wt[c * K + k] = (ushort_t)f2bf(W[idx]);
  }
  if (APPLY) {
    for (int k = tid; k < K; k += 256) {
      float m = sums[k] / (float)N_NODES;
      float v = sums[64 + k] / (float)N_NODES - m * m;
      float s = gamma[k] * rsqrtf(v + BN_EPS);
      scs[k] = s;
      shs[k] = beta[k] - m * s;
    }
  }
  __syncthreads();

  const int rowbase = blockIdx.x * 64;
  const int grow = rowbase + wv * 16 + lm;
  const bool valid = grow < nrows;
  f32x4 acc0 = {0.f, 0.f, 0.f, 0.f};
  f32x4 acc1 = acc0, acc2 = acc0, acc3 = acc0;

#pragma unroll
  for (int k0 = 0; k0 < K; k0 += 32) {
    int kbase = k0 + lq * 8;
    bf16x8 a = {0, 0, 0, 0, 0, 0, 0, 0};
    if (valid) {
      if (XBF16) {
        uint4 u = *(const uint4*)((const char*)Xv + ((size_t)grow * 64 + kbase) * 2);
        if (APPLY) {
          float4 sc0 = *(const float4*)&scs[kbase];
          float4 sc1 = *(const float4*)&scs[kbase + 4];
          float4 sh0 = *(const float4*)&shs[kbase];
          float4 sh1 = *(const float4*)&shs[kbase + 4];
          float f0 = bflo(u.x) * sc0.x + sh0.x, f1 = bfhi(u.x) * sc0.y + sh0.y;
          float f2 = bflo(u.y) * sc0.z + sh0.z, f3 = bfhi(u.y) * sc0.w + sh0.w;
          float f4 = bflo(u.z) * sc1.x + sh1.x, f5 = bfhi(u.z) * sc1.y + sh1.y;
          float f6 = bflo(u.w) * sc1.z + sh1.z, f7 = bfhi(u.w) * sc1.w + sh1.w;
          if (RELU) {
            f0 = fmaxf(f0, 0.f); f1 = fmaxf(f1, 0.f);
            f2 = fmaxf(f2, 0.f); f3 = fmaxf(f3, 0.f);
            f4 = fmaxf(f4, 0.f); f5 = fmaxf(f5, 0.f);
            f6 = fmaxf(f6, 0.f); f7 = fmaxf(f7, 0.f);
          }
          a[0] = (short)f2bf(f0); a[1] = (short)f2bf(f1);
          a[2] = (short)f2bf(f2); a[3] = (short)f2bf(f3);
          a[4] = (short)f2bf(f4); a[5] = (short)f2bf(f5);
          a[6] = (short)f2bf(f6); a[7] = (short)f2bf(f7);
        } else {
          a = *(const bf16x8*)&u;
        }
      } else {
        const float* xp = (const float*)Xv + (size_t)grow * K + kbase;
        float4 xa = *(const float4*)xp;
        float4 xb = *(const float4*)(xp + 4);
        a[0] = (short)f2bf(xa.x); a[1] = (short)f2bf(xa.y);
        a[2] = (short)f2bf(xa.z); a[3] = (short)f2bf(xa.w);
        a[4] = (short)f2bf(xb.x); a[5] = (short)f2bf(xb.y);
        a[6] = (short)f2bf(xb.z); a[7] = (short)f2bf(xb.w);
      }
    }
    bf16x8 b0 = *(const bf16x8*)(wt + (0 + lm) * K + kbase);
    bf16x8 b1 = *(const bf16x8*)(wt + (16 + lm) * K + kbase);
    bf16x8 b2 = *(const bf16x8*)(wt + (32 + lm) * K + kbase);
    bf16x8 b3 = *(const bf16x8*)(wt + (48 + lm) * K + kbase);
    acc0 = __builtin_amdgcn_mfma_f32_16x16x32_bf16(a, b0, acc0, 0, 0, 0);
    acc1 = __builtin_amdgcn_mfma_f32_16x16x32_bf16(a, b1, acc1, 0, 0, 0);
    acc2 = __builtin_amdgcn_mfma_f32_16x16x32_bf16(a, b2, acc2, 0, 0, 0);
    acc3 = __builtin_amdgcn_mfma_f32_16x16x32_bf16(a, b3, acc3, 0, 0, 0);
  }

#pragma unroll
  for (int r = 0; r < 4; ++r) {
    int rr = wv * 16 + lq * 4 + r;
    redo[rr * 65 + lm] = acc0[r];
    redo[rr * 65 + 16 + lm] = acc1[r];
    redo[rr * 65 + 32 + lm] = acc2[r];
    redo[rr * 65 + 48 + lm] = acc3[r];
  }
  __syncthreads();
  {
    int r = tid >> 2;
    int cq = (tid & 3) * 16;
    int gr = rowbase + r;
    if (gr < nrows) {
      float dn = dinv[gr];
      const float* sp = &redo[r * 65 + cq];
      unsigned p[8];
#pragma unroll
      for (int i = 0; i < 8; ++i)
        p[i] = f2bf(sp[2 * i] * dn) | (f2bf(sp[2 * i + 1] * dn) << 16);
      char* ob = (char*)out + ((size_t)gr * 64 + cq) * 2;
      *(uint4*)ob = make_uint4(p[0], p[1], p[2], p[3]);
      *(uint4*)(ob + 16) = make_uint4(p[4], p[5], p[6], p[7]);
    }
  }
}

// ---------------- aggregation: src-quartile phased + 4-node interleave + sentinel row ----------------
// Each 16-lane group owns 4 consecutive nodes (fp32 register accumulators).
// The grid sweeps src-quartiles p=0..3 so the concurrent gather working set is
// 25K rows = 3.2 MB < 4 MB per-XCD L2 (FETCH 157->116 MB, verified r1/r2).
// Out-of-segment slots gather from a single zeroed SENTINEL row (hs[N_NODES])
// instead of clamped in-segment duplicates with AND-masks: dead gathers become
// same-address L1 hits (no L2/fabric request bytes -- the r2 bottleneck) and
// the per-edge mask VALU disappears (sentinel zeros add exactly +0.0).
// POOL=true (layer 3): skip the global out-write and fuse raw graph pooling
// (sum + count per graph) via block-local LDS; BN3 affine applied in classify_k.

template <bool POOL>
__global__ __launch_bounds__(256) void agg_k(
    const ushort_t* __restrict__ hs, const float* __restrict__ dinv,
    const int* __restrict__ rp4, const int* __restrict__ csr,
    const float* __restrict__ bias, ushort_t* __restrict__ out,
    float* __restrict__ sums, const int* __restrict__ batch,
    float* __restrict__ psum, float* __restrict__ pcnt) {
  const int tid = threadIdx.x;
  const int w = tid >> 6;
  const int lane = tid & 63;
  const int g = lane >> 4;     // node-group slot within wave
  const int q = lane & 15;     // feature quad
  const char* hb = (const char*)hs;
  char* ob = (char*)out;
  const int qo = q << 3;

  __shared__ float rs[16][64];
  __shared__ float rs2[16][64];
  __shared__ float pl[POOL ? 64 * 64 : 1];
  __shared__ float pcl[POOL ? 64 : 1];
  if (POOL) {
    for (int i = tid; i < 64 * 64; i += 256) pl[i] = 0.f;
    if (tid < 64) pcl[tid] = 0.f;
    __syncthreads();
  }

  const int nb = blockIdx.x * 64 + (w * 4 + g) * 4;  // first of 4 nodes

  int4 rp[4];
  int en[4];
#pragma unroll
  for (int i = 0; i < 4; ++i) {
    int n = nb + i;
    if (n < N_NODES) {
      rp[i] = *(const int4*)(rp4 + 4 * n);
      en[i] = rp4[4 * n + 4];
    } else {
      rp[i] = make_int4(0, 0, 0, 0);
      en[i] = 0;
    }
  }
  float4 bval = *(const float4*)(bias + q * 4);
  float4 acc0 = make_float4(0.f, 0.f, 0.f, 0.f);
  float4 acc1 = acc0, acc2 = acc0, acc3 = acc0;

#define ACCV(A, V) { \
    A.x += bflo((V).x); A.y += bfhi((V).x); A.z += bflo((V).y); A.w += bfhi((V).y); }
// sentinel-selected csr fetch: in-bounds -> csr[j]; OOB -> zeroed row offset
#define EFETCH(J, H) ((J) < (H) ? csr[(J)] : (int)SENT_OFF)

#pragma unroll
  for (int p = 0; p < 4; ++p) {
    int j0 = (p == 0) ? rp[0].x : (p == 1) ? rp[0].y : (p == 2) ? rp[0].z : rp[0].w;
    int h0 = (p == 3) ? en[0] : ((p == 0) ? rp[0].y : (p == 1) ? rp[0].z : rp[0].w);
    int j1 = (p == 0) ? rp[1].x : (p == 1) ? rp[1].y : (p == 2) ? rp[1].z : rp[1].w;
    int h1 = (p == 3) ? en[1] : ((p == 0) ? rp[1].y : (p == 1) ? rp[1].z : rp[1].w);
    int j2 = (p == 0) ? rp[2].x : (p == 1) ? rp[2].y : (p == 2) ? rp[2].z : rp[2].w;
    int h2 = (p == 3) ? en[2] : ((p == 0) ? rp[2].y : (p == 1) ? rp[2].z : rp[2].w);
    int j3 = (p == 0) ? rp[3].x : (p == 1) ? rp[3].y : (p == 2) ? rp[3].z : rp[3].w;
    int h3 = (p == 3) ? en[3] : ((p == 0) ? rp[3].y : (p == 1) ? rp[3].z : rp[3].w);

    int mrem = max(max(h0 - j0, h1 - j1), max(h2 - j2, h3 - j3));
    int iters = (mrem + 1) >> 1;
    if (iters > 0) {
      // prologue: first csr batch (OOB slots -> sentinel row)
      int e00 = EFETCH(j0, h0);
      int e01 = EFETCH(j0 + 1, h0);
      int e10 = EFETCH(j1, h1);
      int e11 = EFETCH(j1 + 1, h1);
      int e20 = EFETCH(j2, h2);
      int e21 = EFETCH(j2 + 1, h2);
      int e30 = EFETCH(j3, h3);
      int e31 = EFETCH(j3 + 1, h3);
      for (int it = 0; it < iters; ++it) {
        // 8 gathers in flight (dead slots hit the L1-hot sentinel row)
        uint2 v00 = *(const uint2*)(hb + (size_t)(unsigned)e00 + qo);
        uint2 v01 = *(const uint2*)(hb + (size_t)(unsigned)e01 + qo);
        uint2 v10 = *(const uint2*)(hb + (size_t)(unsigned)e10 + qo);
        uint2 v11 = *(const uint2*)(hb + (size_t)(unsigned)e11 + qo);
        uint2 v20 = *(const uint2*)(hb + (size_t)(unsigned)e20 + qo);
        uint2 v21 = *(const uint2*)(hb + (size_t)(unsigned)e21 + qo);
        uint2 v30 = *(const uint2*)(hb + (size_t)(unsigned)e30 + qo);
        uint2 v31 = *(const uint2*)(hb + (size_t)(unsigned)e31 + qo);
        j0 += 2; j1 += 2; j2 += 2; j3 += 2;
        // prefetch next csr batch while gathers are in flight
        e00 = EFETCH(j0, h0);
        e01 = EFETCH(j0 + 1, h0);
        e10 = EFETCH(j1, h1);
        e11 = EFETCH(j1 + 1, h1);
        e20 = EFETCH(j2, h2);
        e21 = EFETCH(j2 + 1, h2);
        e30 = EFETCH(j3, h3);
        e31 = EFETCH(j3 + 1, h3);
        // accumulate (no masks: sentinel contributes exact +0.0)
        ACCV(acc0, v00) ACCV(acc0, v01)
        ACCV(acc1, v10) ACCV(acc1, v11)
        ACCV(acc2, v20) ACCV(acc2, v21)
        ACCV(acc3, v30) ACCV(acc3, v31)
      }
    }
  }
#undef ACCV
#undef EFETCH

  float4 s = make_float4(0.f, 0.f, 0.f, 0.f);
  float4 s2 = make_float4(0.f, 0.f, 0.f, 0.f);
  int curg = -1, pcount = 0;
  float4 pacc = make_float4(0.f, 0.f, 0.f, 0.f);
#pragma unroll
  for (int i = 0; i < 4; ++i) {
    int n = nb + i;
    if (n < N_NODES) {
      float4 ai = (i == 0) ? acc0 : (i == 1) ? acc1 : (i == 2) ? acc2 : acc3;
      uint2 su = *(const uint2*)(hb + ((size_t)n << 7) + qo);
      float dn = dinv[n];
      float4 a;
      a.x = (ai.x + bflo(su.x)) * dn + bval.x;
      a.y = (ai.y + bfhi(su.x)) * dn + bval.y;
      a.z = (ai.z + bflo(su.y)) * dn + bval.z;
      a.w = (ai.w + bfhi(su.y)) * dn + bval.w;
      if (!POOL) {
        uint2 o;
        o.x = f2bf(a.x) | (f2bf(a.y) << 16);
        o.y = f2bf(a.z) | (f2bf(a.w) << 16);
        *(uint2*)(ob + ((size_t)n << 7) + qo) = o;
      } else {
        int gi = batch[n];  // uniform across the 16-lane group
        if (gi != curg) {
          if (pcount) {
            atomicAdd(&pl[curg * 64 + (q << 2)], pacc.x);
            atomicAdd(&pl[curg * 64 + (q << 2) + 1], pacc.y);
            atomicAdd(&pl[curg * 64 + (q << 2) + 2], pacc.z);
            atomicAdd(&pl[curg * 64 + (q << 2) + 3], pacc.w);
            if (q == 0) atomicAdd(&pcl[curg], (float)pcount);
          }
          curg = gi;
          pacc = a;
          pcount = 1;
        } else {
          pacc.x += a.x; pacc.y += a.y; pacc.z += a.z; pacc.w += a.w;
          pcount++;
        }
      }
      s.x += a.x; s.y += a.y; s.z += a.z; s.w += a.w;
      s2.x += a.x * a.x; s2.y += a.y * a.y;
      s2.z += a.z * a.z; s2.w += a.w * a.w;
    }
  }
  if (POOL && pcount) {
    atomicAdd(&pl[curg * 64 + (q << 2)], pacc.x);
    atomicAdd(&pl[curg * 64 + (q << 2) + 1], pacc.y);
    atomicAdd(&pl[curg * 64 + (q << 2) + 2], pacc.z);
    atomicAdd(&pl[curg * 64 + (q << 2) + 3], pacc.w);
    if (q == 0) atomicAdd(&pcl[curg], (float)pcount);
  }

  *(float4*)(&rs[w * 4 + g][q * 4]) = s;
  *(float4*)(&rs2[w * 4 + g][q * 4]) = s2;
  __syncthreads();
  int c = tid & 63;
  int r0_ = tid >> 6;
  float a = rs[r0_][c] + rs[r0_ + 4][c] + rs[r0_ + 8][c] + rs[r0_ + 12][c];
  float a2 = rs2[r0_][c] + rs2[r0_ + 4][c] + rs2[r0_ + 8][c] + rs2[r0_ + 12][c];
  __syncthreads();
  rs[r0_][c] = a;
  rs2[r0_][c] = a2;
  __syncthreads();
  if (r0_ == 0) {
    atomicAdd(&sums[c], rs[0][c] + rs[1][c] + rs[2][c] + rs[3][c]);
    atomicAdd(&sums[64 + c], rs2[0][c] + rs2[1][c] + rs2[2][c] + rs2[3][c]);
  }
  if (POOL) {
    for (int idx = tid; idx < 64 * 64; idx += 256) {
      int gi = idx >> 6;
      if (pcl[gi] != 0.f) atomicAdd(&psum[idx], pl[idx]);
    }
    if (tid < 64 && pcl[tid] != 0.f) atomicAdd(&pcnt[tid], pcl[tid]);
  }
}

// ---------------- centroid classifier (BN3 affine applied here) ----------------

__global__ void classify_k(const float* __restrict__ psum, const float* __restrict__ pcnt,
                           const float* __restrict__ sums, const float* __restrict__ gamma,
                           const float* __restrict__ beta,
                           const float* __restrict__ cg_, const float* __restrict__ cm,
                           const float* __restrict__ temp, float* __restrict__ out) {
  int g = blockIdx.x;
  int t = threadIdx.x;
  __shared__ float emb[64];
  __shared__ float dist[208];
  if (t < 64) {
    float m = sums[t] / (float)N_NODES;
    float v = sums[64 + t] / (float)N_NODES - m * m;
    float sc = gamma[t] * rsqrtf(v + BN_EPS);
    float sh = beta[t] - m * sc;
    // mean(BN(a)) = sc*mean(a) + sh  (affine commutes with the mean)
    emb[t] = psum[g * 64 + t] / fmaxf(pcnt[g], 1.0f) * sc + sh;
  }
  __syncthreads();
  if (t < 197) {
    const float* C = (t < 5) ? (cg_ + t * 64) : (cm + (t - 5) * 64);
    float d = 0.f;
#pragma unroll 8
    for (int k = 0; k < 64; ++k) {
      float df = emb[k] - C[k];
      d += df * df;
    }
    dist[t] = d;
  }
  __syncthreads();
  float tv = temp[0];
  if (t == 64) {
    float m = dist[0];
    for (int j = 1; j < 5; ++j) m = fminf(m, dist[j]);
    out[g * 65] = -m / tv;
  }
  if (t < 64) {
    float m = fminf(dist[5 + t * 3], fminf(dist[5 + t * 3 + 1], dist[5 + t * 3 + 2]));
    out[g * 65 + 1 + t] = -m / tv;
  }
}

// ---------------- launch ----------------

extern "C" void kernel_launch(void* const* d_in, const int* in_sizes, int n_in,
                              void* d_out, int out_size, void* d_ws, size_t ws_size,
                              hipStream_t stream) {
  const float* x   = (const float*)d_in[0];
  const int* ei    = (const int*)d_in[1];
  const int* batch = (const int*)d_in[2];
  const float* W1 = (const float*)d_in[3];  const float* b1 = (const float*)d_in[4];
  const float* g1 = (const float*)d_in[5];  const float* be1 = (const float*)d_in[6];
  const float* W2 = (const float*)d_in[7];  const float* b2 = (const float*)d_in[8];
  const float* g2 = (const float*)d_in[9];  const float* be2 = (const float*)d_in[10];
  const float* W3 = (const float*)d_in[11]; const float* b3 = (const float*)d_in[12];
  const float* g3 = (const float*)d_in[13]; const float* be3 = (const float*)d_in[14];
  const float* cg_ = (const float*)d_in[15];
  const float* cm = (const float*)d_in[16];
  const float* temp = (const float*)d_in[17];
  float* out = (float*)d_out;

  char* ws = (char*)d_ws;
  size_t off = 0;
  auto alloc = [&](size_t bytes) -> void* {
    void* p = ws + off;
    off = (off + bytes + 255) & ~(size_t)255;
    return p;
  };
  // zero-init block first -> single memset
  int* gh        = (int*)alloc((size_t)NPB * 4);
  float* sumsAll = (float*)alloc(3 * 128 * 4);
  float* psum    = (float*)alloc(64 * 64 * 4);
  float* pcnt    = (float*)alloc(64 * 4);
  size_t zero_end = off;
  int* boff      = (int*)alloc((size_t)(NPB + 1) * 4);
  int* gcur      = (int*)alloc((size_t)NPB * 4);
  unsigned* tmp  = (unsigned*)alloc((size_t)N_EDGES * 4);
  int* csr       = (int*)alloc((size_t)N_EDGES * 4);
  int* rp4       = (int*)alloc((size_t)(4 * N_NODES + 1) * 4);
  float* dinv    = (float*)alloc((size_t)N_NODES * 4);
  ushort_t* hA   = (ushort_t*)alloc((size_t)(N_NODES + 1) * 64 * 2);  // bf16 hs + sentinel row
  ushort_t* hB   = (ushort_t*)alloc((size_t)N_NODES * 64 * 2);        // bf16 h (pre-BN)

  hipMemsetAsync(ws, 0, zero_end, stream);
  hipMemsetAsync(hA + (size_t)N_NODES * 64, 0, 128, stream);  // zero sentinel row

  const int NB_GEMM = (N_NODES + 63) / 64;   // 1563

  // CSR build
  ghist_k<<<512, 256, 0, stream>>>(ei, gh);
  gscan_k<<<1, 256, 0, stream>>>(gh, boff, gcur);
  part_k<<<PART_BLOCKS, 512, 0, stream>>>(ei, gcur, tmp);
  bwork_k<<<NPB, 512, 0, stream>>>(tmp, boff, rp4, dinv, csr);

  // layer 1 (MFMA, fp32 X -> bf16 frags)
  gemm_k<IN_DIM, false, false, false><<<NB_GEMM, 256, 0, stream>>>(x, W1, nullptr, nullptr, nullptr, dinv, hA, N_NODES);
  agg_k<false><<<NB_AGG, 256, 0, stream>>>(hA, dinv, rp4, csr, b1, hB, sumsAll, nullptr, nullptr, nullptr);

  // layer 2 (BN1+ReLU inline from sums, bf16 input)
  gemm_k<HID, true, true, true><<<NB_GEMM, 256, 0, stream>>>(hB, W2, sumsAll, g1, be1, dinv, hA, N_NODES);
  agg_k<false><<<NB_AGG, 256, 0, stream>>>(hA, dinv, rp4, csr, b2, hB, sumsAll + 128, nullptr, nullptr, nullptr);

  // layer 3 (BN2+ReLU inline from sums, bf16 input); agg fuses raw pooling
  gemm_k<HID, true, true, true><<<NB_GEMM, 256, 0, stream>>>(hB, W3, sumsAll + 128, g2, be2, dinv, hA, N_NODES);
  agg_k<true><<<NB_AGG, 256, 0, stream>>>(hA, dinv, rp4, csr, b3, nullptr, sumsAll + 256, batch, psum, pcnt);

  // classify (BN3 affine inline from sums)
  classify_k<<<N_GRAPHS, 256, 0, stream>>>(psum, pcnt, sumsAll + 256, g3, be3, cg_, cm, temp, out);
}

// Round 4
// 501.297 us; speedup vs baseline: 1.2906x; 1.0229x over previous
//
#include <hip/hip_runtime.h>
#include <math.h>

#define N_NODES 100000
#define N_EDGES 3200000
#define N_GRAPHS 64
#define IN_DIM 128
#define HID 64
#define BN_EPS 1e-5f

#define PSHIFT 9
#define PBS 512
#define NPB ((N_NODES + PBS - 1) / PBS)  // 196
#define PART_BLOCKS 256
#define CHUNK_E (N_EDGES / PART_BLOCKS)  // 12500 (multiple of 4)

#define QBOUND 25000
#define NB_AGG ((N_NODES + 63) / 64)  // 1563: 32 subgroups/block x 2 nodes/subgroup
#define SENT_OFF (N_NODES << 7)       // byte offset of zeroed sentinel row in hs

typedef unsigned short ushort_t;
typedef __attribute__((ext_vector_type(8))) short bf16x8;
typedef __attribute__((ext_vector_type(4))) float f32x4;

__device__ __forceinline__ float bflo(unsigned u) { return __uint_as_float(u << 16); }
__device__ __forceinline__ float bfhi(unsigned u) { return __uint_as_float(u & 0xFFFF0000u); }
__device__ __forceinline__ float bfu(ushort_t u) { return __uint_as_float((unsigned)u << 16); }
__device__ __forceinline__ unsigned f2bf(float f) {  // RNE
  unsigned u = __float_as_uint(f);
  return (u + 0x7FFFu + ((u >> 16) & 1u)) >> 16;
}

// ---------------- CSR build: two-level bucket sort, int4-vectorized ----------------

__global__ __launch_bounds__(256) void ghist_k(const int* __restrict__ ei,
                                               int* __restrict__ gh) {
  __shared__ int h[NPB];
  for (int i = threadIdx.x; i < NPB; i += 256) h[i] = 0;
  __syncthreads();
  const int4* d4 = (const int4*)(ei + N_EDGES);
  int n4 = N_EDGES / 4;
  int stride = gridDim.x * 256;
  for (int i = blockIdx.x * 256 + threadIdx.x; i < n4; i += stride) {
    int4 d = d4[i];
    atomicAdd(&h[d.x >> PSHIFT], 1);
    atomicAdd(&h[d.y >> PSHIFT], 1);
    atomicAdd(&h[d.z >> PSHIFT], 1);
    atomicAdd(&h[d.w >> PSHIFT], 1);
  }
  __syncthreads();
  for (int i = threadIdx.x; i < NPB; i += 256) {
    int v = h[i];
    if (v) atomicAdd(&gh[i], v);
  }
}

__global__ __launch_bounds__(256) void gscan_k(const int* __restrict__ gh,
                                               int* __restrict__ boff,
                                               int* __restrict__ gcur) {
  __shared__ int sa[256], sb[256];
  int t = threadIdx.x;
  int v = (t < NPB) ? gh[t] : 0;
  sa[t] = v;
  __syncthreads();
  int* src = sa; int* dst = sb;
  for (int o = 1; o < 256; o <<= 1) {
    dst[t] = src[t] + ((t >= o) ? src[t - o] : 0);
    __syncthreads();
    int* tmp = src; src = dst; dst = tmp;
  }
  if (t < NPB) {
    int excl = src[t] - v;
    boff[t] = excl;
    gcur[t] = excl;
    if (t == NPB - 1) boff[NPB] = src[t];
  }
}

__global__ __launch_bounds__(512) void part_k(const int* __restrict__ ei,
                                              int* __restrict__ gcur,
                                              unsigned* __restrict__ tmp) {
  __shared__ int lh[NPB];
  __shared__ int lcur[NPB];
  int t = threadIdx.x;
  for (int i = t; i < NPB; i += 512) lh[i] = 0;
  __syncthreads();
  int q0 = blockIdx.x * (CHUNK_E / 4);
  int q1 = q0 + CHUNK_E / 4;
  const int4* d4 = (const int4*)(ei + N_EDGES);
  const int4* s4 = (const int4*)ei;
  for (int i = q0 + t; i < q1; i += 512) {
    int4 d = d4[i];
    atomicAdd(&lh[d.x >> PSHIFT], 1);
    atomicAdd(&lh[d.y >> PSHIFT], 1);
    atomicAdd(&lh[d.z >> PSHIFT], 1);
    atomicAdd(&lh[d.w >> PSHIFT], 1);
  }
  __syncthreads();
  for (int i = t; i < NPB; i += 512) {
    int v = lh[i];
    lcur[i] = v ? atomicAdd(&gcur[i], v) : 0;
  }
  __syncthreads();
  for (int i = q0 + t; i < q1; i += 512) {
    int4 d = d4[i];
    int4 s = s4[i];
    int b0 = d.x >> PSHIFT, b1 = d.y >> PSHIFT, b2 = d.z >> PSHIFT, b3 = d.w >> PSHIFT;
    int p0 = atomicAdd(&lcur[b0], 1);
    int p1 = atomicAdd(&lcur[b1], 1);
    int p2 = atomicAdd(&lcur[b2], 1);
    int p3 = atomicAdd(&lcur[b3], 1);
    tmp[p0] = ((unsigned)(d.x & (PBS - 1)) << 17) | (unsigned)s.x;
    tmp[p1] = ((unsigned)(d.y & (PBS - 1)) << 17) | (unsigned)s.y;
    tmp[p2] = ((unsigned)(d.z & (PBS - 1)) << 17) | (unsigned)s.z;
    tmp[p3] = ((unsigned)(d.w & (PBS - 1)) << 17) | (unsigned)s.w;
  }
}

// fused per-bucket: histogram per (node, src-quartile) -> rp4/dinv -> place
// rp4[4n+k] = start of node n's src-quartile-k segment (quartile-sorted CSR)
__global__ __launch_bounds__(512) void bwork_k(
    const unsigned* __restrict__ tmp, const int* __restrict__ boff,
    int* __restrict__ rp4, float* __restrict__ dinv, int* __restrict__ csr) {
  int b = blockIdx.x;
  int base = boff[b], end = boff[b + 1];
  int t = threadIdx.x;
  __shared__ int cnt[PBS * 4];
  __shared__ int cur[PBS * 4];
  __shared__ int sa[PBS], sb[PBS];
  for (int i = t; i < PBS * 4; i += 512) cnt[i] = 0;
  __syncthreads();
  int a0 = (base + 3) & ~3;
  int a1 = end & ~3;
  if (a1 < a0) { a0 = end; a1 = end; }
  const uint4* t4 = (const uint4*)tmp;
#define HIST1(U) { unsigned u_ = (U); int nl_ = u_ >> 17; int s_ = u_ & 0x1FFFF; \
    int qq_ = (s_ >= QBOUND) + (s_ >= 2*QBOUND) + (s_ >= 3*QBOUND); \
    atomicAdd(&cnt[nl_ * 4 + qq_], 1); }
  if (base + t < a0) HIST1(tmp[base + t]);
  for (int i = a0 / 4 + t; i < a1 / 4; i += 512) {
    uint4 u = t4[i];
    HIST1(u.x) HIST1(u.y) HIST1(u.z) HIST1(u.w)
  }
  if (a1 + t < end) HIST1(tmp[a1 + t]);
#undef HIST1
  __syncthreads();
  int c0 = cnt[t * 4], c1 = cnt[t * 4 + 1], c2 = cnt[t * 4 + 2], c3 = cnt[t * 4 + 3];
  int tsum = c0 + c1 + c2 + c3;
  sa[t] = tsum;
  __syncthreads();
  int* src_ = sa; int* dst_ = sb;
  for (int o = 1; o < PBS; o <<= 1) {
    dst_[t] = src_[t] + ((t >= o) ? src_[t - o] : 0);
    __syncthreads();
    int* z = src_; src_ = dst_; dst_ = z;
  }
  int nb = src_[t] - tsum;
  int o0 = nb, o1 = nb + c0, o2 = nb + c0 + c1, o3 = nb + c0 + c1 + c2;
  cur[t * 4] = o0; cur[t * 4 + 1] = o1; cur[t * 4 + 2] = o2; cur[t * 4 + 3] = o3;
  int n = b * PBS + t;
  if (n < N_NODES) {
    rp4[4 * n] = base + o0;
    rp4[4 * n + 1] = base + o1;
    rp4[4 * n + 2] = base + o2;
    rp4[4 * n + 3] = base + o3;
    dinv[n] = rsqrtf((float)(tsum + 1));  // +1 self loop
    if (n == N_NODES - 1) rp4[4 * N_NODES] = base + nb + tsum;
  }
  __syncthreads();
#define PLACE1(U) { unsigned u_ = (U); int nl_ = u_ >> 17; int s_ = u_ & 0x1FFFF; \
    int qq_ = (s_ >= QBOUND) + (s_ >= 2*QBOUND) + (s_ >= 3*QBOUND); \
    int p_ = atomicAdd(&cur[nl_ * 4 + qq_], 1); \
    csr[base + p_] = s_ << 7; }
  if (base + t < a0) PLACE1(tmp[base + t]);
  for (int i = a0 / 4 + t; i < a1 / 4; i += 512) {
    uint4 u = t4[i];
    PLACE1(u.x) PLACE1(u.y) PLACE1(u.z) PLACE1(u.w)
  }
  if (a1 + t < end) PLACE1(tmp[a1 + t]);
#undef PLACE1
}

// ---------------- MFMA GEMM: hs[n][c] = dinv[n] * (BN(X)[n] @ W)[c] -> bf16 ----------------

template <int K, bool XBF16, bool APPLY, bool RELU>
__global__ __launch_bounds__(256) void gemm_k(
    const void* __restrict__ Xv, const float* __restrict__ W,
    const float* __restrict__ sums, const float* __restrict__ gamma,
    const float* __restrict__ beta, const float* __restrict__ dinv,
    ushort_t* __restrict__ out, int nrows) {
  __shared__ ushort_t wt[64 * K];   // wt[n][k] bf16
  __shared__ float scs[128], shs[128];
  __shared__ float redo[64 * 65];   // D repack, padded
  const int tid = threadIdx.x;
  const int wv = tid >> 6;
  const int lane = tid & 63;
  const int lm = lane & 15;
  const int lq = lane >> 4;

  for (int idx = tid; idx < K * 64; idx += 256) {
    int k = idx >> 6, c = idx & 63;      // W[k][c]
    wt[c * K + k] = (ushort_t)f2bf(W[idx]);
  }
  if (APPLY) {
    for (int k = tid; k < K; k += 256) {
      float m = sums[k] / (float)N_NODES;
      float v = sums[64 + k] / (float)N_NODES - m * m;
      float s = gamma[k] * rsqrtf(v + BN_EPS);
      scs[k] = s;
      shs[k] = beta[k] - m * s;
    }
  }
  __syncthreads();

  const int rowbase = blockIdx.x * 64;
  const int grow = rowbase + wv * 16 + lm;
  const bool valid = grow < nrows;
  f32x4 acc0 = {0.f, 0.f, 0.f, 0.f};
  f32x4 acc1 = acc0, acc2 = acc0, acc3 = acc0;

#pragma unroll
  for (int k0 = 0; k0 < K; k0 += 32) {
    int kbase = k0 + lq * 8;
    bf16x8 a = {0, 0, 0, 0, 0, 0, 0, 0};
    if (valid) {
      if (XBF16) {
        uint4 u = *(const uint4*)((const char*)Xv + ((size_t)grow * 64 + kbase) * 2);
        if (APPLY) {
          float4 sc0 = *(const float4*)&scs[kbase];
          float4 sc1 = *(const float4*)&scs[kbase + 4];
          float4 sh0 = *(const float4*)&shs[kbase];
          float4 sh1 = *(const float4*)&shs[kbase + 4];
          float f0 = bflo(u.x) * sc0.x + sh0.x, f1 = bfhi(u.x) * sc0.y + sh0.y;
          float f2 = bflo(u.y) * sc0.z + sh0.z, f3 = bfhi(u.y) * sc0.w + sh0.w;
          float f4 = bflo(u.z) * sc1.x + sh1.x, f5 = bfhi(u.z) * sc1.y + sh1.y;
          float f6 = bflo(u.w) * sc1.z + sh1.z, f7 = bfhi(u.w) * sc1.w + sh1.w;
          if (RELU) {
            f0 = fmaxf(f0, 0.f); f1 = fmaxf(f1, 0.f);
            f2 = fmaxf(f2, 0.f); f3 = fmaxf(f3, 0.f);
            f4 = fmaxf(f4, 0.f); f5 = fmaxf(f5, 0.f);
            f6 = fmaxf(f6, 0.f); f7 = fmaxf(f7, 0.f);
          }
          a[0] = (short)f2bf(f0); a[1] = (short)f2bf(f1);
          a[2] = (short)f2bf(f2); a[3] = (short)f2bf(f3);
          a[4] = (short)f2bf(f4); a[5] = (short)f2bf(f5);
          a[6] = (short)f2bf(f6); a[7] = (short)f2bf(f7);
        } else {
          a = *(const bf16x8*)&u;
        }
      } else {
        const float* xp = (const float*)Xv + (size_t)grow * K + kbase;
        float4 xa = *(const float4*)xp;
        float4 xb = *(const float4*)(xp + 4);
        a[0] = (short)f2bf(xa.x); a[1] = (short)f2bf(xa.y);
        a[2] = (short)f2bf(xa.z); a[3] = (short)f2bf(xa.w);
        a[4] = (short)f2bf(xb.x); a[5] = (short)f2bf(xb.y);
        a[6] = (short)f2bf(xb.z); a[7] = (short)f2bf(xb.w);
      }
    }
    bf16x8 b0 = *(const bf16x8*)(wt + (0 + lm) * K + kbase);
    bf16x8 b1 = *(const bf16x8*)(wt + (16 + lm) * K + kbase);
    bf16x8 b2 = *(const bf16x8*)(wt + (32 + lm) * K + kbase);
    bf16x8 b3 = *(const bf16x8*)(wt + (48 + lm) * K + kbase);
    acc0 = __builtin_amdgcn_mfma_f32_16x16x32_bf16(a, b0, acc0, 0, 0, 0);
    acc1 = __builtin_amdgcn_mfma_f32_16x16x32_bf16(a, b1, acc1, 0, 0, 0);
    acc2 = __builtin_amdgcn_mfma_f32_16x16x32_bf16(a, b2, acc2, 0, 0, 0);
    acc3 = __builtin_amdgcn_mfma_f32_16x16x32_bf16(a, b3, acc3, 0, 0, 0);
  }

#pragma unroll
  for (int r = 0; r < 4; ++r) {
    int rr = wv * 16 + lq * 4 + r;
    redo[rr * 65 + lm] = acc0[r];
    redo[rr * 65 + 16 + lm] = acc1[r];
    redo[rr * 65 + 32 + lm] = acc2[r];
    redo[rr * 65 + 48 + lm] = acc3[r];
  }
  __syncthreads();
  {
    int r = tid >> 2;
    int cq = (tid & 3) * 16;
    int gr = rowbase + r;
    if (gr < nrows) {
      float dn = dinv[gr];
      const float* sp = &redo[r * 65 + cq];
      unsigned p[8];
#pragma unroll
      for (int i = 0; i < 8; ++i)
        p[i] = f2bf(sp[2 * i] * dn) | (f2bf(sp[2 * i + 1] * dn) << 16);
      char* ob = (char*)out + ((size_t)gr * 64 + cq) * 2;
      *(uint4*)ob = make_uint4(p[0], p[1], p[2], p[3]);
      *(uint4*)(ob + 16) = make_uint4(p[4], p[5], p[6], p[7]);
    }
  }
}

// ---------------- aggregation: phased + 8-lane x uint4 rows (half the gather instructions) ----------------
// r0-r3 all converge on ~88 us with byte/VALU-reduction exhausted -> hypothesis:
// vector-memory INSTRUCTION count is the binding resource. New geometry: each
// row is read by 8 lanes x 16 B (uint4) instead of 16 lanes x 8 B, so one load
// instruction delivers 8 rows x 128 B = 1024 B (was 512 B): gather and csr
// instruction counts halve at identical bytes/segments. Each 8-lane subgroup
// owns 2 consecutive nodes (64 nodes/block, grid unchanged); quartile phasing
// (L2-resident working set) and the zeroed sentinel row for tail slots are
// retained. POOL=true (layer 3): skip the global out-write and fuse raw graph
// pooling via block-local LDS; BN3 affine applied in classify_k.

template <bool POOL>
__global__ __launch_bounds__(256) void agg_k(
    const ushort_t* __restrict__ hs, const float* __restrict__ dinv,
    const int* __restrict__ rp4, const int* __restrict__ csr,
    const float* __restrict__ bias, ushort_t* __restrict__ out,
    float* __restrict__ sums, const int* __restrict__ batch,
    float* __restrict__ psum, float* __restrict__ pcnt) {
  const int tid = threadIdx.x;
  const int w = tid >> 6;
  const int lane = tid & 63;
  const int g = lane >> 3;     // subgroup 0..7
  const int f = lane & 7;      // feature octet: bytes [f*16, f*16+16)
  const char* hb = (const char*)hs;
  char* ob = (char*)out;
  const int qo = f << 4;

  __shared__ float rs[32][64];               // reused for s then s2
  __shared__ float pl[POOL ? 64 * 64 : 1];
  __shared__ float pcl[POOL ? 64 : 1];
  if (POOL) {
    for (int i = tid; i < 64 * 64; i += 256) pl[i] = 0.f;
    if (tid < 64) pcl[tid] = 0.f;
    __syncthreads();
  }

  const int nb = blockIdx.x * 64 + (w * 8 + g) * 2;  // first of 2 nodes

  int4 rpa, rpb;
  int ena, enb;
  if (nb < N_NODES) {
    rpa = *(const int4*)(rp4 + 4 * nb);
    ena = rp4[4 * nb + 4];
  } else {
    rpa = make_int4(0, 0, 0, 0); ena = 0;
  }
  if (nb + 1 < N_NODES) {
    rpb = *(const int4*)(rp4 + 4 * (nb + 1));
    enb = rp4[4 * (nb + 1) + 4];
  } else {
    rpb = make_int4(0, 0, 0, 0); enb = 0;
  }

  float4 bvA = *(const float4*)(bias + f * 8);
  float4 bvB = *(const float4*)(bias + f * 8 + 4);
  float4 aA0 = make_float4(0.f, 0.f, 0.f, 0.f);
  float4 aB0 = aA0, aA1 = aA0, aB1 = aA0;

#define ACCU4(AA, AB, U) { \
    AA.x += bflo((U).x); AA.y += bfhi((U).x); AA.z += bflo((U).y); AA.w += bfhi((U).y); \
    AB.x += bflo((U).z); AB.y += bfhi((U).z); AB.z += bflo((U).w); AB.w += bfhi((U).w); }
// sentinel-selected csr fetch: in-bounds -> csr[j]; OOB -> zeroed row offset
#define EFETCH(J, H) ((J) < (H) ? csr[(J)] : (int)SENT_OFF)

#pragma unroll
  for (int p = 0; p < 4; ++p) {
    int j0 = (p == 0) ? rpa.x : (p == 1) ? rpa.y : (p == 2) ? rpa.z : rpa.w;
    int h0 = (p == 3) ? ena : ((p == 0) ? rpa.y : (p == 1) ? rpa.z : rpa.w);
    int j1 = (p == 0) ? rpb.x : (p == 1) ? rpb.y : (p == 2) ? rpb.z : rpb.w;
    int h1 = (p == 3) ? enb : ((p == 0) ? rpb.y : (p == 1) ? rpb.z : rpb.w);

    int mrem = max(h0 - j0, h1 - j1);
    int iters = (mrem + 1) >> 1;
    if (iters > 0) {
      int e00 = EFETCH(j0, h0);
      int e01 = EFETCH(j0 + 1, h0);
      int e10 = EFETCH(j1, h1);
      int e11 = EFETCH(j1 + 1, h1);
      for (int it = 0; it < iters; ++it) {
        // 4 dwordx4 gathers in flight; each instruction serves all 8 subgroups
        uint4 v00 = *(const uint4*)(hb + (size_t)(unsigned)e00 + qo);
        uint4 v01 = *(const uint4*)(hb + (size_t)(unsigned)e01 + qo);
        uint4 v10 = *(const uint4*)(hb + (size_t)(unsigned)e10 + qo);
        uint4 v11 = *(const uint4*)(hb + (size_t)(unsigned)e11 + qo);
        j0 += 2; j1 += 2;
        // prefetch next csr batch while gathers are in flight
        e00 = EFETCH(j0, h0);
        e01 = EFETCH(j0 + 1, h0);
        e10 = EFETCH(j1, h1);
        e11 = EFETCH(j1 + 1, h1);
        // accumulate (sentinel contributes exact +0.0)
        ACCU4(aA0, aB0, v00) ACCU4(aA0, aB0, v01)
        ACCU4(aA1, aB1, v10) ACCU4(aA1, aB1, v11)
      }
    }
  }
#undef ACCU4
#undef EFETCH

  float4 sA = make_float4(0.f, 0.f, 0.f, 0.f), sB = sA;
  float4 s2A = sA, s2B = sA;
  int curg = -1, pcount = 0;
  float4 pA = sA, pB = sA;
#pragma unroll
  for (int i = 0; i < 2; ++i) {
    int n = nb + i;
    if (n < N_NODES) {
      float4 cA = i ? aA1 : aA0;
      float4 cB = i ? aB1 : aB0;
      uint4 su = *(const uint4*)(hb + ((size_t)n << 7) + qo);
      float dn = dinv[n];
      float4 a, b;
      a.x = (cA.x + bflo(su.x)) * dn + bvA.x;
      a.y = (cA.y + bfhi(su.x)) * dn + bvA.y;
      a.z = (cA.z + bflo(su.y)) * dn + bvA.z;
      a.w = (cA.w + bfhi(su.y)) * dn + bvA.w;
      b.x = (cB.x + bflo(su.z)) * dn + bvB.x;
      b.y = (cB.y + bfhi(su.z)) * dn + bvB.y;
      b.z = (cB.z + bflo(su.w)) * dn + bvB.z;
      b.w = (cB.w + bfhi(su.w)) * dn + bvB.w;
      if (!POOL) {
        uint4 o;
        o.x = f2bf(a.x) | (f2bf(a.y) << 16);
        o.y = f2bf(a.z) | (f2bf(a.w) << 16);
        o.z = f2bf(b.x) | (f2bf(b.y) << 16);
        o.w = f2bf(b.z) | (f2bf(b.w) << 16);
        *(uint4*)(ob + ((size_t)n << 7) + qo) = o;
      } else {
        int gi = batch[n];  // uniform across the 8-lane subgroup
        if (gi != curg) {
          if (pcount) {
            atomicAdd(&pl[curg * 64 + f * 8 + 0], pA.x);
            atomicAdd(&pl[curg * 64 + f * 8 + 1], pA.y);
            atomicAdd(&pl[curg * 64 + f * 8 + 2], pA.z);
            atomicAdd(&pl[curg * 64 + f * 8 + 3], pA.w);
            atomicAdd(&pl[curg * 64 + f * 8 + 4], pB.x);
            atomicAdd(&pl[curg * 64 + f * 8 + 5], pB.y);
            atomicAdd(&pl[curg * 64 + f * 8 + 6], pB.z);
            atomicAdd(&pl[curg * 64 + f * 8 + 7], pB.w);
            if (f == 0) atomicAdd(&pcl[curg], (float)pcount);
          }
          curg = gi;
          pA = a; pB = b;
          pcount = 1;
        } else {
          pA.x += a.x; pA.y += a.y; pA.z += a.z; pA.w += a.w;
          pB.x += b.x; pB.y += b.y; pB.z += b.z; pB.w += b.w;
          pcount++;
        }
      }
      sA.x += a.x; sA.y += a.y; sA.z += a.z; sA.w += a.w;
      sB.x += b.x; sB.y += b.y; sB.z += b.z; sB.w += b.w;
      s2A.x += a.x * a.x; s2A.y += a.y * a.y; s2A.z += a.z * a.z; s2A.w += a.w * a.w;
      s2B.x += b.x * b.x; s2B.y += b.y * b.y; s2B.z += b.z * b.z; s2B.w += b.w * b.w;
    }
  }
  if (POOL && pcount) {
    atomicAdd(&pl[curg * 64 + f * 8 + 0], pA.x);
    atomicAdd(&pl[curg * 64 + f * 8 + 1], pA.y);
    atomicAdd(&pl[curg * 64 + f * 8 + 2], pA.z);
    atomicAdd(&pl[curg * 64 + f * 8 + 3], pA.w);
    atomicAdd(&pl[curg * 64 + f * 8 + 4], pB.x);
    atomicAdd(&pl[curg * 64 + f * 8 + 5], pB.y);
    atomicAdd(&pl[curg * 64 + f * 8 + 6], pB.z);
    atomicAdd(&pl[curg * 64 + f * 8 + 7], pB.w);
    if (f == 0) atomicAdd(&pcl[curg], (float)pcount);
  }

  // block reduce of s (pass 1) then s2 (pass 2), reusing rs
  const int row = w * 8 + g;
  const int c = tid & 63;
  const int r_ = tid >> 6;
  *(float4*)(&rs[row][f * 8]) = sA;
  *(float4*)(&rs[row][f * 8 + 4]) = sB;
  __syncthreads();
  {
    float a = 0.f;
#pragma unroll
    for (int k = 0; k < 8; ++k) a += rs[r_ + 4 * k][c];
    __syncthreads();
    rs[r_][c] = a;
    __syncthreads();
    if (r_ == 0) atomicAdd(&sums[c], rs[0][c] + rs[1][c] + rs[2][c] + rs[3][c]);
    __syncthreads();
  }
  *(float4*)(&rs[row][f * 8]) = s2A;
  *(float4*)(&rs[row][f * 8 + 4]) = s2B;
  __syncthreads();
  {
    float a = 0.f;
#pragma unroll
    for (int k = 0; k < 8; ++k) a += rs[r_ + 4 * k][c];
    __syncthreads();
    rs[r_][c] = a;
    __syncthreads();
    if (r_ == 0) atomicAdd(&sums[64 + c], rs[0][c] + rs[1][c] + rs[2][c] + rs[3][c]);
  }

  if (POOL) {
    __syncthreads();
    for (int idx = tid; idx < 64 * 64; idx += 256) {
      int gi = idx >> 6;
      if (pcl[gi] != 0.f) atomicAdd(&psum[idx], pl[idx]);
    }
    if (tid < 64 && pcl[tid] != 0.f) atomicAdd(&pcnt[tid], pcl[tid]);
  }
}

// ---------------- centroid classifier (BN3 affine applied here) ----------------

__global__ void classify_k(const float* __restrict__ psum, const float* __restrict__ pcnt,
                           const float* __restrict__ sums, const float* __restrict__ gamma,
                           const float* __restrict__ beta,
                           const float* __restrict__ cg_, const float* __restrict__ cm,
                           const float* __restrict__ temp, float* __restrict__ out) {
  int g = blockIdx.x;
  int t = threadIdx.x;
  __shared__ float emb[64];
  __shared__ float dist[208];
  if (t < 64) {
    float m = sums[t] / (float)N_NODES;
    float v = sums[64 + t] / (float)N_NODES - m * m;
    float sc = gamma[t] * rsqrtf(v + BN_EPS);
    float sh = beta[t] - m * sc;
    // mean(BN(a)) = sc*mean(a) + sh  (affine commutes with the mean)
    emb[t] = psum[g * 64 + t] / fmaxf(pcnt[g], 1.0f) * sc + sh;
  }
  __syncthreads();
  if (t < 197) {
    const float* C = (t < 5) ? (cg_ + t * 64) : (cm + (t - 5) * 64);
    float d = 0.f;
#pragma unroll 8
    for (int k = 0; k < 64; ++k) {
      float df = emb[k] - C[k];
      d += df * df;
    }
    dist[t] = d;
  }
  __syncthreads();
  float tv = temp[0];
  if (t == 64) {
    float m = dist[0];
    for (int j = 1; j < 5; ++j) m = fminf(m, dist[j]);
    out[g * 65] = -m / tv;
  }
  if (t < 64) {
    float m = fminf(dist[5 + t * 3], fminf(dist[5 + t * 3 + 1], dist[5 + t * 3 + 2]));
    out[g * 65 + 1 + t] = -m / tv;
  }
}

// ---------------- launch ----------------

extern "C" void kernel_launch(void* const* d_in, const int* in_sizes, int n_in,
                              void* d_out, int out_size, void* d_ws, size_t ws_size,
                              hipStream_t stream) {
  const float* x   = (const float*)d_in[0];
  const int* ei    = (const int*)d_in[1];
  const int* batch = (const int*)d_in[2];
  const float* W1 = (const float*)d_in[3];  const float* b1 = (const float*)d_in[4];
  const float* g1 = (const float*)d_in[5];  const float* be1 = (const float*)d_in[6];
  const float* W2 = (const float*)d_in[7];  const float* b2 = (const float*)d_in[8];
  const float* g2 = (const float*)d_in[9];  const float* be2 = (const float*)d_in[10];
  const float* W3 = (const float*)d_in[11]; const float* b3 = (const float*)d_in[12];
  const float* g3 = (const float*)d_in[13]; const float* be3 = (const float*)d_in[14];
  const float* cg_ = (const float*)d_in[15];
  const float* cm = (const float*)d_in[16];
  const float* temp = (const float*)d_in[17];
  float* out = (float*)d_out;

  char* ws = (char*)d_ws;
  size_t off = 0;
  auto alloc = [&](size_t bytes) -> void* {
    void* p = ws + off;
    off = (off + bytes + 255) & ~(size_t)255;
    return p;
  };
  // zero-init block first -> single memset
  int* gh        = (int*)alloc((size_t)NPB * 4);
  float* sumsAll = (float*)alloc(3 * 128 * 4);
  float* psum    = (float*)alloc(64 * 64 * 4);
  float* pcnt    = (float*)alloc(64 * 4);
  size_t zero_end = off;
  int* boff      = (int*)alloc((size_t)(NPB + 1) * 4);
  int* gcur      = (int*)alloc((size_t)NPB * 4);
  unsigned* tmp  = (unsigned*)alloc((size_t)N_EDGES * 4);
  int* csr       = (int*)alloc((size_t)N_EDGES * 4);
  int* rp4       = (int*)alloc((size_t)(4 * N_NODES + 1) * 4);
  float* dinv    = (float*)alloc((size_t)N_NODES * 4);
  ushort_t* hA   = (ushort_t*)alloc((size_t)(N_NODES + 1) * 64 * 2);  // bf16 hs + sentinel row
  ushort_t* hB   = (ushort_t*)alloc((size_t)N_NODES * 64 * 2);        // bf16 h (pre-BN)

  hipMemsetAsync(ws, 0, zero_end, stream);
  hipMemsetAsync(hA + (size_t)N_NODES * 64, 0, 128, stream);  // zero sentinel row

  const int NB_GEMM = (N_NODES + 63) / 64;   // 1563

  // CSR build
  ghist_k<<<512, 256, 0, stream>>>(ei, gh);
  gscan_k<<<1, 256, 0, stream>>>(gh, boff, gcur);
  part_k<<<PART_BLOCKS, 512, 0, stream>>>(ei, gcur, tmp);
  bwork_k<<<NPB, 512, 0, stream>>>(tmp, boff, rp4, dinv, csr);

  // layer 1 (MFMA, fp32 X -> bf16 frags)
  gemm_k<IN_DIM, false, false, false><<<NB_GEMM, 256, 0, stream>>>(x, W1, nullptr, nullptr, nullptr, dinv, hA, N_NODES);
  agg_k<false><<<NB_AGG, 256, 0, stream>>>(hA, dinv, rp4, csr, b1, hB, sumsAll, nullptr, nullptr, nullptr);

  // layer 2 (BN1+ReLU inline from sums, bf16 input)
  gemm_k<HID, true, true, true><<<NB_GEMM, 256, 0, stream>>>(hB, W2, sumsAll, g1, be1, dinv, hA, N_NODES);
  agg_k<false><<<NB_AGG, 256, 0, stream>>>(hA, dinv, rp4, csr, b2, hB, sumsAll + 128, nullptr, nullptr, nullptr);

  // layer 3 (BN2+ReLU inline from sums, bf16 input); agg fuses raw pooling
  gemm_k<HID, true, true, true><<<NB_GEMM, 256, 0, stream>>>(hB, W3, sumsAll + 128, g2, be2, dinv, hA, N_NODES);
  agg_k<true><<<NB_AGG, 256, 0, stream>>>(hA, dinv, rp4, csr, b3, nullptr, sumsAll + 256, batch, psum, pcnt);

  // classify (BN3 affine inline from sums)
  classify_k<<<N_GRAPHS, 256, 0, stream>>>(psum, pcnt, sumsAll + 256, g3, be3, cg_, cm, temp, out);
}

// Round 6
// 472.734 us; speedup vs baseline: 1.3686x; 1.0604x over previous
//
#include <hip/hip_runtime.h>
#include <math.h>

#define N_NODES 100000
#define N_EDGES 3200000
#define N_GRAPHS 64
#define IN_DIM 128
#define HID 64
#define BN_EPS 1e-5f

#define PSHIFT 9
#define PBS 512
#define NPB ((N_NODES + PBS - 1) / PBS)  // 196
#define PART_BLOCKS 256
#define CHUNK_E (N_EDGES / PART_BLOCKS)  // 12500 (multiple of 4)

#define QBOUND 25000
#define NB_AGG ((N_NODES + 63) / 64)  // 1563: 32 subgroups/block x 2 nodes/subgroup
#define SENT_OFF (N_NODES << 7)       // byte offset of zeroed sentinel row in hs

typedef unsigned short ushort_t;
typedef __attribute__((ext_vector_type(8))) short bf16x8;
typedef __attribute__((ext_vector_type(4))) float f32x4;

__device__ __forceinline__ float bflo(unsigned u) { return __uint_as_float(u << 16); }
__device__ __forceinline__ float bfhi(unsigned u) { return __uint_as_float(u & 0xFFFF0000u); }
__device__ __forceinline__ float bfu(ushort_t u) { return __uint_as_float((unsigned)u << 16); }
__device__ __forceinline__ unsigned f2bf(float f) {  // RNE
  unsigned u = __float_as_uint(f);
  return (u + 0x7FFFu + ((u >> 16) & 1u)) >> 16;
}

// ---------------- CSR build: two-level bucket sort, int4-vectorized ----------------
// (r5's fixed-capacity variant crashed -- likely workspace overrun; reverted to
// the r4-verified exact-prefix layout.)

__global__ __launch_bounds__(256) void ghist_k(const int* __restrict__ ei,
                                               int* __restrict__ gh) {
  __shared__ int h[NPB];
  for (int i = threadIdx.x; i < NPB; i += 256) h[i] = 0;
  __syncthreads();
  const int4* d4 = (const int4*)(ei + N_EDGES);
  int n4 = N_EDGES / 4;
  int stride = gridDim.x * 256;
  for (int i = blockIdx.x * 256 + threadIdx.x; i < n4; i += stride) {
    int4 d = d4[i];
    atomicAdd(&h[d.x >> PSHIFT], 1);
    atomicAdd(&h[d.y >> PSHIFT], 1);
    atomicAdd(&h[d.z >> PSHIFT], 1);
    atomicAdd(&h[d.w >> PSHIFT], 1);
  }
  __syncthreads();
  for (int i = threadIdx.x; i < NPB; i += 256) {
    int v = h[i];
    if (v) atomicAdd(&gh[i], v);
  }
}

__global__ __launch_bounds__(256) void gscan_k(const int* __restrict__ gh,
                                               int* __restrict__ boff,
                                               int* __restrict__ gcur) {
  __shared__ int sa[256], sb[256];
  int t = threadIdx.x;
  int v = (t < NPB) ? gh[t] : 0;
  sa[t] = v;
  __syncthreads();
  int* src = sa; int* dst = sb;
  for (int o = 1; o < 256; o <<= 1) {
    dst[t] = src[t] + ((t >= o) ? src[t - o] : 0);
    __syncthreads();
    int* tmp = src; src = dst; dst = tmp;
  }
  if (t < NPB) {
    int excl = src[t] - v;
    boff[t] = excl;
    gcur[t] = excl;
    if (t == NPB - 1) boff[NPB] = src[t];
  }
}

__global__ __launch_bounds__(512) void part_k(const int* __restrict__ ei,
                                              int* __restrict__ gcur,
                                              unsigned* __restrict__ tmp) {
  __shared__ int lh[NPB];
  __shared__ int lcur[NPB];
  int t = threadIdx.x;
  for (int i = t; i < NPB; i += 512) lh[i] = 0;
  __syncthreads();
  int q0 = blockIdx.x * (CHUNK_E / 4);
  int q1 = q0 + CHUNK_E / 4;
  const int4* d4 = (const int4*)(ei + N_EDGES);
  const int4* s4 = (const int4*)ei;
  for (int i = q0 + t; i < q1; i += 512) {
    int4 d = d4[i];
    atomicAdd(&lh[d.x >> PSHIFT], 1);
    atomicAdd(&lh[d.y >> PSHIFT], 1);
    atomicAdd(&lh[d.z >> PSHIFT], 1);
    atomicAdd(&lh[d.w >> PSHIFT], 1);
  }
  __syncthreads();
  for (int i = t; i < NPB; i += 512) {
    int v = lh[i];
    lcur[i] = v ? atomicAdd(&gcur[i], v) : 0;
  }
  __syncthreads();
  for (int i = q0 + t; i < q1; i += 512) {
    int4 d = d4[i];
    int4 s = s4[i];
    int b0 = d.x >> PSHIFT, b1 = d.y >> PSHIFT, b2 = d.z >> PSHIFT, b3 = d.w >> PSHIFT;
    int p0 = atomicAdd(&lcur[b0], 1);
    int p1 = atomicAdd(&lcur[b1], 1);
    int p2 = atomicAdd(&lcur[b2], 1);
    int p3 = atomicAdd(&lcur[b3], 1);
    tmp[p0] = ((unsigned)(d.x & (PBS - 1)) << 17) | (unsigned)s.x;
    tmp[p1] = ((unsigned)(d.y & (PBS - 1)) << 17) | (unsigned)s.y;
    tmp[p2] = ((unsigned)(d.z & (PBS - 1)) << 17) | (unsigned)s.z;
    tmp[p3] = ((unsigned)(d.w & (PBS - 1)) << 17) | (unsigned)s.w;
  }
}

// fused per-bucket: histogram per (node, src-quartile) -> rp4/dinv -> place
// rp4[4n+k] = start of node n's src-quartile-k segment (quartile-sorted CSR)
__global__ __launch_bounds__(512) void bwork_k(
    const unsigned* __restrict__ tmp, const int* __restrict__ boff,
    int* __restrict__ rp4, float* __restrict__ dinv, int* __restrict__ csr) {
  int b = blockIdx.x;
  int base = boff[b], end = boff[b + 1];
  int t = threadIdx.x;
  __shared__ int cnt[PBS * 4];
  __shared__ int cur[PBS * 4];
  __shared__ int sa[PBS], sb[PBS];
  for (int i = t; i < PBS * 4; i += 512) cnt[i] = 0;
  __syncthreads();
  int a0 = (base + 3) & ~3;
  int a1 = end & ~3;
  if (a1 < a0) { a0 = end; a1 = end; }
  const uint4* t4 = (const uint4*)tmp;
#define HIST1(U) { unsigned u_ = (U); int nl_ = u_ >> 17; int s_ = u_ & 0x1FFFF; \
    int qq_ = (s_ >= QBOUND) + (s_ >= 2*QBOUND) + (s_ >= 3*QBOUND); \
    atomicAdd(&cnt[nl_ * 4 + qq_], 1); }
  if (base + t < a0) HIST1(tmp[base + t]);
  for (int i = a0 / 4 + t; i < a1 / 4; i += 512) {
    uint4 u = t4[i];
    HIST1(u.x) HIST1(u.y) HIST1(u.z) HIST1(u.w)
  }
  if (a1 + t < end) HIST1(tmp[a1 + t]);
#undef HIST1
  __syncthreads();
  int c0 = cnt[t * 4], c1 = cnt[t * 4 + 1], c2 = cnt[t * 4 + 2], c3 = cnt[t * 4 + 3];
  int tsum = c0 + c1 + c2 + c3;
  sa[t] = tsum;
  __syncthreads();
  int* src_ = sa; int* dst_ = sb;
  for (int o = 1; o < PBS; o <<= 1) {
    dst_[t] = src_[t] + ((t >= o) ? src_[t - o] : 0);
    __syncthreads();
    int* z = src_; src_ = dst_; dst_ = z;
  }
  int nb = src_[t] - tsum;
  int o0 = nb, o1 = nb + c0, o2 = nb + c0 + c1, o3 = nb + c0 + c1 + c2;
  cur[t * 4] = o0; cur[t * 4 + 1] = o1; cur[t * 4 + 2] = o2; cur[t * 4 + 3] = o3;
  int n = b * PBS + t;
  if (n < N_NODES) {
    rp4[4 * n] = base + o0;
    rp4[4 * n + 1] = base + o1;
    rp4[4 * n + 2] = base + o2;
    rp4[4 * n + 3] = base + o3;
    dinv[n] = rsqrtf((float)(tsum + 1));  // +1 self loop
    if (n == N_NODES - 1) rp4[4 * N_NODES] = base + nb + tsum;
  }
  __syncthreads();
#define PLACE1(U) { unsigned u_ = (U); int nl_ = u_ >> 17; int s_ = u_ & 0x1FFFF; \
    int qq_ = (s_ >= QBOUND) + (s_ >= 2*QBOUND) + (s_ >= 3*QBOUND); \
    int p_ = atomicAdd(&cur[nl_ * 4 + qq_], 1); \
    csr[base + p_] = s_ << 7; }
  if (base + t < a0) PLACE1(tmp[base + t]);
  for (int i = a0 / 4 + t; i < a1 / 4; i += 512) {
    uint4 u = t4[i];
    PLACE1(u.x) PLACE1(u.y) PLACE1(u.z) PLACE1(u.w)
  }
  if (a1 + t < end) PLACE1(tmp[a1 + t]);
#undef PLACE1
}

// ---------------- MFMA GEMM: hs[n][c] = dinv[n] * (BN(X)[n] @ W)[c] -> bf16 ----------------

template <int K, bool XBF16, bool APPLY, bool RELU>
__global__ __launch_bounds__(256) void gemm_k(
    const void* __restrict__ Xv, const float* __restrict__ W,
    const float* __restrict__ sums, const float* __restrict__ gamma,
    const float* __restrict__ beta, const float* __restrict__ dinv,
    ushort_t* __restrict__ out, int nrows) {
  __shared__ ushort_t wt[64 * K];   // wt[n][k] bf16
  __shared__ float scs[128], shs[128];
  __shared__ float redo[64 * 65];   // D repack, padded
  const int tid = threadIdx.x;
  const int wv = tid >> 6;
  const int lane = tid & 63;
  const int lm = lane & 15;
  const int lq = lane >> 4;

  for (int idx = tid; idx < K * 64; idx += 256) {
    int k = idx >> 6, c = idx & 63;      // W[k][c]
    wt[c * K + k] = (ushort_t)f2bf(W[idx]);
  }
  if (APPLY) {
    for (int k = tid; k < K; k += 256) {
      float m = sums[k] / (float)N_NODES;
      float v = sums[64 + k] / (float)N_NODES - m * m;
      float s = gamma[k] * rsqrtf(v + BN_EPS);
      scs[k] = s;
      shs[k] = beta[k] - m * s;
    }
  }
  __syncthreads();

  const int rowbase = blockIdx.x * 64;
  const int grow = rowbase + wv * 16 + lm;
  const bool valid = grow < nrows;
  f32x4 acc0 = {0.f, 0.f, 0.f, 0.f};
  f32x4 acc1 = acc0, acc2 = acc0, acc3 = acc0;

#pragma unroll
  for (int k0 = 0; k0 < K; k0 += 32) {
    int kbase = k0 + lq * 8;
    bf16x8 a = {0, 0, 0, 0, 0, 0, 0, 0};
    if (valid) {
      if (XBF16) {
        uint4 u = *(const uint4*)((const char*)Xv + ((size_t)grow * 64 + kbase) * 2);
        if (APPLY) {
          float4 sc0 = *(const float4*)&scs[kbase];
          float4 sc1 = *(const float4*)&scs[kbase + 4];
          float4 sh0 = *(const float4*)&shs[kbase];
          float4 sh1 = *(const float4*)&shs[kbase + 4];
          float f0 = bflo(u.x) * sc0.x + sh0.x, f1 = bfhi(u.x) * sc0.y + sh0.y;
          float f2 = bflo(u.y) * sc0.z + sh0.z, f3 = bfhi(u.y) * sc0.w + sh0.w;
          float f4 = bflo(u.z) * sc1.x + sh1.x, f5 = bfhi(u.z) * sc1.y + sh1.y;
          float f6 = bflo(u.w) * sc1.z + sh1.z, f7 = bfhi(u.w) * sc1.w + sh1.w;
          if (RELU) {
            f0 = fmaxf(f0, 0.f); f1 = fmaxf(f1, 0.f);
            f2 = fmaxf(f2, 0.f); f3 = fmaxf(f3, 0.f);
            f4 = fmaxf(f4, 0.f); f5 = fmaxf(f5, 0.f);
            f6 = fmaxf(f6, 0.f); f7 = fmaxf(f7, 0.f);
          }
          a[0] = (short)f2bf(f0); a[1] = (short)f2bf(f1);
          a[2] = (short)f2bf(f2); a[3] = (short)f2bf(f3);
          a[4] = (short)f2bf(f4); a[5] = (short)f2bf(f5);
          a[6] = (short)f2bf(f6); a[7] = (short)f2bf(f7);
        } else {
          a = *(const bf16x8*)&u;
        }
      } else {
        const float* xp = (const float*)Xv + (size_t)grow * K + kbase;
        float4 xa = *(const float4*)xp;
        float4 xb = *(const float4*)(xp + 4);
        a[0] = (short)f2bf(xa.x); a[1] = (short)f2bf(xa.y);
        a[2] = (short)f2bf(xa.z); a[3] = (short)f2bf(xa.w);
        a[4] = (short)f2bf(xb.x); a[5] = (short)f2bf(xb.y);
        a[6] = (short)f2bf(xb.z); a[7] = (short)f2bf(xb.w);
      }
    }
    bf16x8 b0 = *(const bf16x8*)(wt + (0 + lm) * K + kbase);
    bf16x8 b1 = *(const bf16x8*)(wt + (16 + lm) * K + kbase);
    bf16x8 b2 = *(const bf16x8*)(wt + (32 + lm) * K + kbase);
    bf16x8 b3 = *(const bf16x8*)(wt + (48 + lm) * K + kbase);
    acc0 = __builtin_amdgcn_mfma_f32_16x16x32_bf16(a, b0, acc0, 0, 0, 0);
    acc1 = __builtin_amdgcn_mfma_f32_16x16x32_bf16(a, b1, acc1, 0, 0, 0);
    acc2 = __builtin_amdgcn_mfma_f32_16x16x32_bf16(a, b2, acc2, 0, 0, 0);
    acc3 = __builtin_amdgcn_mfma_f32_16x16x32_bf16(a, b3, acc3, 0, 0, 0);
  }

#pragma unroll
  for (int r = 0; r < 4; ++r) {
    int rr = wv * 16 + lq * 4 + r;
    redo[rr * 65 + lm] = acc0[r];
    redo[rr * 65 + 16 + lm] = acc1[r];
    redo[rr * 65 + 32 + lm] = acc2[r];
    redo[rr * 65 + 48 + lm] = acc3[r];
  }
  __syncthreads();
  {
    int r = tid >> 2;
    int cq = (tid & 3) * 16;
    int gr = rowbase + r;
    if (gr < nrows) {
      float dn = dinv[gr];
      const float* sp = &redo[r * 65 + cq];
      unsigned p[8];
#pragma unroll
      for (int i = 0; i < 8; ++i)
        p[i] = f2bf(sp[2 * i] * dn) | (f2bf(sp[2 * i + 1] * dn) << 16);
      char* ob = (char*)out + ((size_t)gr * 64 + cq) * 2;
      *(uint4*)ob = make_uint4(p[0], p[1], p[2], p[3]);
      *(uint4*)(ob + 16) = make_uint4(p[4], p[5], p[6], p[7]);
    }
  }
}

// ---------------- aggregation: phased + 8-lane x uint4 rows + DEPTH-8 pipeline ----------------
// r0-r4 converge at ~4.5 TB/s of L1-miss service (410 MB compulsory misses in
// ~88-95 us) with bytes/instructions/VALU ruled out as the limiter. The knob
// that correlated with time is per-wave outstanding-gather depth (r3 depth-8 =
// 88.4, r4 depth-4 = 95.5). This round isolates depth: uint4 geometry (fewest
// instructions) with 4-edge lookahead per node x 2 nodes = 8 dwordx4 gathers in
// flight per wave (128 cachelines, 2x r4). Quartile phasing (L2-resident
// working set) and the zeroed sentinel row for tail slots retained.
// POOL=true (layer 3): skip the global out-write and fuse raw graph pooling via
// block-local LDS; BN3 affine applied in classify_k.

template <bool POOL>
__global__ __launch_bounds__(256) void agg_k(
    const ushort_t* __restrict__ hs, const float* __restrict__ dinv,
    const int* __restrict__ rp4, const int* __restrict__ csr,
    const float* __restrict__ bias, ushort_t* __restrict__ out,
    float* __restrict__ sums, const int* __restrict__ batch,
    float* __restrict__ psum, float* __restrict__ pcnt) {
  const int tid = threadIdx.x;
  const int w = tid >> 6;
  const int lane = tid & 63;
  const int g = lane >> 3;     // subgroup 0..7
  const int f = lane & 7;      // feature octet: bytes [f*16, f*16+16)
  const char* hb = (const char*)hs;
  char* ob = (char*)out;
  const int qo = f << 4;

  __shared__ float rs[32][64];               // reused for s then s2
  __shared__ float pl[POOL ? 64 * 64 : 1];
  __shared__ float pcl[POOL ? 64 : 1];
  if (POOL) {
    for (int i = tid; i < 64 * 64; i += 256) pl[i] = 0.f;
    if (tid < 64) pcl[tid] = 0.f;
    __syncthreads();
  }

  const int nb = blockIdx.x * 64 + (w * 8 + g) * 2;  // first of 2 nodes

  int4 rpa, rpb;
  int ena, enb;
  if (nb < N_NODES) {
    rpa = *(const int4*)(rp4 + 4 * nb);
    ena = rp4[4 * nb + 4];
  } else {
    rpa = make_int4(0, 0, 0, 0); ena = 0;
  }
  if (nb + 1 < N_NODES) {
    rpb = *(const int4*)(rp4 + 4 * (nb + 1));
    enb = rp4[4 * (nb + 1) + 4];
  } else {
    rpb = make_int4(0, 0, 0, 0); enb = 0;
  }

  float4 bvA = *(const float4*)(bias + f * 8);
  float4 bvB = *(const float4*)(bias + f * 8 + 4);
  float4 aA0 = make_float4(0.f, 0.f, 0.f, 0.f);
  float4 aB0 = aA0, aA1 = aA0, aB1 = aA0;

#define ACCU4(AA, AB, U) { \
    AA.x += bflo((U).x); AA.y += bfhi((U).x); AA.z += bflo((U).y); AA.w += bfhi((U).y); \
    AB.x += bflo((U).z); AB.y += bfhi((U).z); AB.z += bflo((U).w); AB.w += bfhi((U).w); }
// sentinel-selected csr fetch: in-bounds -> csr[j]; OOB -> zeroed row offset
#define EFETCH(J, H) ((J) < (H) ? csr[(J)] : (int)SENT_OFF)

#pragma unroll
  for (int p = 0; p < 4; ++p) {
    int j0 = (p == 0) ? rpa.x : (p == 1) ? rpa.y : (p == 2) ? rpa.z : rpa.w;
    int h0 = (p == 3) ? ena : ((p == 0) ? rpa.y : (p == 1) ? rpa.z : rpa.w);
    int j1 = (p == 0) ? rpb.x : (p == 1) ? rpb.y : (p == 2) ? rpb.z : rpb.w;
    int h1 = (p == 3) ? enb : ((p == 0) ? rpb.y : (p == 1) ? rpb.z : rpb.w);

    int mrem = max(h0 - j0, h1 - j1);
    int iters = (mrem + 3) >> 2;
    if (iters > 0) {
      int e00 = EFETCH(j0, h0);
      int e01 = EFETCH(j0 + 1, h0);
      int e02 = EFETCH(j0 + 2, h0);
      int e03 = EFETCH(j0 + 3, h0);
      int e10 = EFETCH(j1, h1);
      int e11 = EFETCH(j1 + 1, h1);
      int e12 = EFETCH(j1 + 2, h1);
      int e13 = EFETCH(j1 + 3, h1);
      for (int it = 0; it < iters; ++it) {
        // 8 dwordx4 gathers in flight (128 cachelines per wave)
        uint4 v00 = *(const uint4*)(hb + (size_t)(unsigned)e00 + qo);
        uint4 v01 = *(const uint4*)(hb + (size_t)(unsigned)e01 + qo);
        uint4 v02 = *(const uint4*)(hb + (size_t)(unsigned)e02 + qo);
        uint4 v03 = *(const uint4*)(hb + (size_t)(unsigned)e03 + qo);
        uint4 v10 = *(const uint4*)(hb + (size_t)(unsigned)e10 + qo);
        uint4 v11 = *(const uint4*)(hb + (size_t)(unsigned)e11 + qo);
        uint4 v12 = *(const uint4*)(hb + (size_t)(unsigned)e12 + qo);
        uint4 v13 = *(const uint4*)(hb + (size_t)(unsigned)e13 + qo);
        j0 += 4; j1 += 4;
        // prefetch next csr batch while gathers are in flight
        e00 = EFETCH(j0, h0);
        e01 = EFETCH(j0 + 1, h0);
        e02 = EFETCH(j0 + 2, h0);
        e03 = EFETCH(j0 + 3, h0);
        e10 = EFETCH(j1, h1);
        e11 = EFETCH(j1 + 1, h1);
        e12 = EFETCH(j1 + 2, h1);
        e13 = EFETCH(j1 + 3, h1);
        // accumulate (sentinel contributes exact +0.0)
        ACCU4(aA0, aB0, v00) ACCU4(aA0, aB0, v01)
        ACCU4(aA0, aB0, v02) ACCU4(aA0, aB0, v03)
        ACCU4(aA1, aB1, v10) ACCU4(aA1, aB1, v11)
        ACCU4(aA1, aB1, v12) ACCU4(aA1, aB1, v13)
      }
    }
  }
#undef ACCU4
#undef EFETCH

  float4 sA = make_float4(0.f, 0.f, 0.f, 0.f), sB = sA;
  float4 s2A = sA, s2B = sA;
  int curg = -1, pcount = 0;
  float4 pA = sA, pB = sA;
#pragma unroll
  for (int i = 0; i < 2; ++i) {
    int n = nb + i;
    if (n < N_NODES) {
      float4 cA = i ? aA1 : aA0;
      float4 cB = i ? aB1 : aB0;
      uint4 su = *(const uint4*)(hb + ((size_t)n << 7) + qo);
      float dn = dinv[n];
      float4 a, b;
      a.x = (cA.x + bflo(su.x)) * dn + bvA.x;
      a.y = (cA.y + bfhi(su.x)) * dn + bvA.y;
      a.z = (cA.z + bflo(su.y)) * dn + bvA.z;
      a.w = (cA.w + bfhi(su.y)) * dn + bvA.w;
      b.x = (cB.x + bflo(su.z)) * dn + bvB.x;
      b.y = (cB.y + bfhi(su.z)) * dn + bvB.y;
      b.z = (cB.z + bflo(su.w)) * dn + bvB.z;
      b.w = (cB.w + bfhi(su.w)) * dn + bvB.w;
      if (!POOL) {
        uint4 o;
        o.x = f2bf(a.x) | (f2bf(a.y) << 16);
        o.y = f2bf(a.z) | (f2bf(a.w) << 16);
        o.z = f2bf(b.x) | (f2bf(b.y) << 16);
        o.w = f2bf(b.z) | (f2bf(b.w) << 16);
        *(uint4*)(ob + ((size_t)n << 7) + qo) = o;
      } else {
        int gi = batch[n];  // uniform across the 8-lane subgroup
        if (gi != curg) {
          if (pcount) {
            atomicAdd(&pl[curg * 64 + f * 8 + 0], pA.x);
            atomicAdd(&pl[curg * 64 + f * 8 + 1], pA.y);
            atomicAdd(&pl[curg * 64 + f * 8 + 2], pA.z);
            atomicAdd(&pl[curg * 64 + f * 8 + 3], pA.w);
            atomicAdd(&pl[curg * 64 + f * 8 + 4], pB.x);
            atomicAdd(&pl[curg * 64 + f * 8 + 5], pB.y);
            atomicAdd(&pl[curg * 64 + f * 8 + 6], pB.z);
            atomicAdd(&pl[curg * 64 + f * 8 + 7], pB.w);
            if (f == 0) atomicAdd(&pcl[curg], (float)pcount);
          }
          curg = gi;
          pA = a; pB = b;
          pcount = 1;
        } else {
          pA.x += a.x; pA.y += a.y; pA.z += a.z; pA.w += a.w;
          pB.x += b.x; pB.y += b.y; pB.z += b.z; pB.w += b.w;
          pcount++;
        }
      }
      sA.x += a.x; sA.y += a.y; sA.z += a.z; sA.w += a.w;
      sB.x += b.x; sB.y += b.y; sB.z += b.z; sB.w += b.w;
      s2A.x += a.x * a.x; s2A.y += a.y * a.y; s2A.z += a.z * a.z; s2A.w += a.w * a.w;
      s2B.x += b.x * b.x; s2B.y += b.y * b.y; s2B.z += b.z * b.z; s2B.w += b.w * b.w;
    }
  }
  if (POOL && pcount) {
    atomicAdd(&pl[curg * 64 + f * 8 + 0], pA.x);
    atomicAdd(&pl[curg * 64 + f * 8 + 1], pA.y);
    atomicAdd(&pl[curg * 64 + f * 8 + 2], pA.z);
    atomicAdd(&pl[curg * 64 + f * 8 + 3], pA.w);
    atomicAdd(&pl[curg * 64 + f * 8 + 4], pB.x);
    atomicAdd(&pl[curg * 64 + f * 8 + 5], pB.y);
    atomicAdd(&pl[curg * 64 + f * 8 + 6], pB.z);
    atomicAdd(&pl[curg * 64 + f * 8 + 7], pB.w);
    if (f == 0) atomicAdd(&pcl[curg], (float)pcount);
  }

  // block reduce of s (pass 1) then s2 (pass 2), reusing rs
  const int row = w * 8 + g;
  const int c = tid & 63;
  const int r_ = tid >> 6;
  *(float4*)(&rs[row][f * 8]) = sA;
  *(float4*)(&rs[row][f * 8 + 4]) = sB;
  __syncthreads();
  {
    float a = 0.f;
#pragma unroll
    for (int k = 0; k < 8; ++k) a += rs[r_ + 4 * k][c];
    __syncthreads();
    rs[r_][c] = a;
    __syncthreads();
    if (r_ == 0) atomicAdd(&sums[c], rs[0][c] + rs[1][c] + rs[2][c] + rs[3][c]);
    __syncthreads();
  }
  *(float4*)(&rs[row][f * 8]) = s2A;
  *(float4*)(&rs[row][f * 8 + 4]) = s2B;
  __syncthreads();
  {
    float a = 0.f;
#pragma unroll
    for (int k = 0; k < 8; ++k) a += rs[r_ + 4 * k][c];
    __syncthreads();
    rs[r_][c] = a;
    __syncthreads();
    if (r_ == 0) atomicAdd(&sums[64 + c], rs[0][c] + rs[1][c] + rs[2][c] + rs[3][c]);
  }

  if (POOL) {
    __syncthreads();
    for (int idx = tid; idx < 64 * 64; idx += 256) {
      int gi = idx >> 6;
      if (pcl[gi] != 0.f) atomicAdd(&psum[idx], pl[idx]);
    }
    if (tid < 64 && pcl[tid] != 0.f) atomicAdd(&pcnt[tid], pcl[tid]);
  }
}

// ---------------- centroid classifier (BN3 affine applied here) ----------------

__global__ void classify_k(const float* __restrict__ psum, const float* __restrict__ pcnt,
                           const float* __restrict__ sums, const float* __restrict__ gamma,
                           const float* __restrict__ beta,
                           const float* __restrict__ cg_, const float* __restrict__ cm,
                           const float* __restrict__ temp, float* __restrict__ out) {
  int g = blockIdx.x;
  int t = threadIdx.x;
  __shared__ float emb[64];
  __shared__ float dist[208];
  if (t < 64) {
    float m = sums[t] / (float)N_NODES;
    float v = sums[64 + t] / (float)N_NODES - m * m;
    float sc = gamma[t] * rsqrtf(v + BN_EPS);
    float sh = beta[t] - m * sc;
    // mean(BN(a)) = sc*mean(a) + sh  (affine commutes with the mean)
    emb[t] = psum[g * 64 + t] / fmaxf(pcnt[g], 1.0f) * sc + sh;
  }
  __syncthreads();
  if (t < 197) {
    const float* C = (t < 5) ? (cg_ + t * 64) : (cm + (t - 5) * 64);
    float d = 0.f;
#pragma unroll 8
    for (int k = 0; k < 64; ++k) {
      float df = emb[k] - C[k];
      d += df * df;
    }
    dist[t] = d;
  }
  __syncthreads();
  float tv = temp[0];
  if (t == 64) {
    float m = dist[0];
    for (int j = 1; j < 5; ++j) m = fminf(m, dist[j]);
    out[g * 65] = -m / tv;
  }
  if (t < 64) {
    float m = fminf(dist[5 + t * 3], fminf(dist[5 + t * 3 + 1], dist[5 + t * 3 + 2]));
    out[g * 65 + 1 + t] = -m / tv;
  }
}

// ---------------- launch ----------------

extern "C" void kernel_launch(void* const* d_in, const int* in_sizes, int n_in,
                              void* d_out, int out_size, void* d_ws, size_t ws_size,
                              hipStream_t stream) {
  const float* x   = (const float*)d_in[0];
  const int* ei    = (const int*)d_in[1];
  const int* batch = (const int*)d_in[2];
  const float* W1 = (const float*)d_in[3];  const float* b1 = (const float*)d_in[4];
  const float* g1 = (const float*)d_in[5];  const float* be1 = (const float*)d_in[6];
  const float* W2 = (const float*)d_in[7];  const float* b2 = (const float*)d_in[8];
  const float* g2 = (const float*)d_in[9];  const float* be2 = (const float*)d_in[10];
  const float* W3 = (const float*)d_in[11]; const float* b3 = (const float*)d_in[12];
  const float* g3 = (const float*)d_in[13]; const float* be3 = (const float*)d_in[14];
  const float* cg_ = (const float*)d_in[15];
  const float* cm = (const float*)d_in[16];
  const float* temp = (const float*)d_in[17];
  float* out = (float*)d_out;

  char* ws = (char*)d_ws;
  size_t off = 0;
  auto alloc = [&](size_t bytes) -> void* {
    void* p = ws + off;
    off = (off + bytes + 255) & ~(size_t)255;
    return p;
  };
  // zero-init block first -> single memset
  int* gh        = (int*)alloc((size_t)NPB * 4);
  float* sumsAll = (float*)alloc(3 * 128 * 4);
  float* psum    = (float*)alloc(64 * 64 * 4);
  float* pcnt    = (float*)alloc(64 * 4);
  size_t zero_end = off;
  int* boff      = (int*)alloc((size_t)(NPB + 1) * 4);
  int* gcur      = (int*)alloc((size_t)NPB * 4);
  unsigned* tmp  = (unsigned*)alloc((size_t)N_EDGES * 4);
  int* csr       = (int*)alloc((size_t)N_EDGES * 4);
  int* rp4       = (int*)alloc((size_t)(4 * N_NODES + 1) * 4);
  float* dinv    = (float*)alloc((size_t)N_NODES * 4);
  ushort_t* hA   = (ushort_t*)alloc((size_t)(N_NODES + 1) * 64 * 2);  // bf16 hs + sentinel row
  ushort_t* hB   = (ushort_t*)alloc((size_t)N_NODES * 64 * 2);        // bf16 h (pre-BN)

  hipMemsetAsync(ws, 0, zero_end, stream);
  hipMemsetAsync(hA + (size_t)N_NODES * 64, 0, 128, stream);  // zero sentinel row

  const int NB_GEMM = (N_NODES + 63) / 64;   // 1563

  // CSR build
  ghist_k<<<512, 256, 0, stream>>>(ei, gh);
  gscan_k<<<1, 256, 0, stream>>>(gh, boff, gcur);
  part_k<<<PART_BLOCKS, 512, 0, stream>>>(ei, gcur, tmp);
  bwork_k<<<NPB, 512, 0, stream>>>(tmp, boff, rp4, dinv, csr);

  // layer 1 (MFMA, fp32 X -> bf16 frags)
  gemm_k<IN_DIM, false, false, false><<<NB_GEMM, 256, 0, stream>>>(x, W1, nullptr, nullptr, nullptr, dinv, hA, N_NODES);
  agg_k<false><<<NB_AGG, 256, 0, stream>>>(hA, dinv, rp4, csr, b1, hB, sumsAll, nullptr, nullptr, nullptr);

  // layer 2 (BN1+ReLU inline from sums, bf16 input)
  gemm_k<HID, true, true, true><<<NB_GEMM, 256, 0, stream>>>(hB, W2, sumsAll, g1, be1, dinv, hA, N_NODES);
  agg_k<false><<<NB_AGG, 256, 0, stream>>>(hA, dinv, rp4, csr, b2, hB, sumsAll + 128, nullptr, nullptr, nullptr);

  // layer 3 (BN2+ReLU inline from sums, bf16 input); agg fuses raw pooling
  gemm_k<HID, true, true, true><<<NB_GEMM, 256, 0, stream>>>(hB, W3, sumsAll + 128, g2, be2, dinv, hA, N_NODES);
  agg_k<true><<<NB_AGG, 256, 0, stream>>>(hA, dinv, rp4, csr, b3, nullptr, sumsAll + 256, batch, psum, pcnt);

  // classify (BN3 affine inline from sums)
  classify_k<<<N_GRAPHS, 256, 0, stream>>>(psum, pcnt, sumsAll + 256, g3, be3, cg_, cm, temp, out);
}